// Round 8
// baseline (687.250 us; speedup 1.0000x reference)
//
#include <hip/hip_runtime.h>

#define BB 8
#define NN 1024
#define DD 512
#define DFFK 1024
#define HH 4
#define RR (BB * NN)     // 8192 rows per model
#define MM (2 * RR)      // 16384 combined rows

typedef unsigned short u16;
typedef u16 u16x8 __attribute__((ext_vector_type(8)));
typedef u16 u16x4 __attribute__((ext_vector_type(4)));
typedef float f32x4 __attribute__((ext_vector_type(4)));
typedef __bf16 bf16x8 __attribute__((ext_vector_type(8)));

__device__ __forceinline__ u16 f32_to_bf16(float f) {
  unsigned int u = __builtin_bit_cast(unsigned int, f);
  unsigned int r = u + 0x7FFFu + ((u >> 16) & 1u);
  return (u16)(r >> 16);
}

__device__ __forceinline__ f32x4 mfma16(u16x8 a, u16x8 b, f32x4 c) {
  return __builtin_amdgcn_mfma_f32_16x16x32_bf16(
      __builtin_bit_cast(bf16x8, a), __builtin_bit_cast(bf16x8, b), c, 0, 0, 0);
}

__device__ __forceinline__ void gl16(u16* lds, const u16* g) {
  __builtin_amdgcn_global_load_lds(
      (const __attribute__((address_space(1))) unsigned int*)g,
      (__attribute__((address_space(3))) unsigned int*)lds, 16, 0, 0);
}

// ---------------- weight convert: nmat matrices W[K][N2] f32 -> Wt[N2][K] bf16 ----------------
__global__ __launch_bounds__(256) void wconv_kernel(const float* __restrict__ W,
                                                    u16* __restrict__ Wt, int K, int N2, int nmat) {
  int idx = blockIdx.x * 256 + threadIdx.x;
  if (idx >= nmat * K * N2) return;
  int mat = idx / (K * N2), rem = idx % (K * N2);
  int k = rem % K, n = rem / K;
  Wt[(size_t)mat * K * N2 + (size_t)n * K + k] =
      f32_to_bf16(W[(size_t)mat * K * N2 + (size_t)k * N2 + n]);
}

// ---------------- input transpose: per batch z, in[R_][C_] -> out[C_][R_] ----------------
__global__ __launch_bounds__(256) void transpose_kernel(const float* __restrict__ in,
                                                        float* __restrict__ out, int R_, int C_) {
  __shared__ float t[32][33];
  int bx = blockIdx.x * 32, by = blockIdx.y * 32;
  size_t zoff = (size_t)blockIdx.z * R_ * C_;
  const float* ip = in + zoff;
  float* op = out + zoff;
  int tx = threadIdx.x, ty = threadIdx.y;
#pragma unroll
  for (int i = 0; i < 32; i += 8)
    t[ty + i][tx] = ip[(size_t)(by + ty + i) * C_ + bx + tx];
  __syncthreads();
#pragma unroll
  for (int i = 0; i < 32; i += 8)
    op[(size_t)(bx + ty + i) * R_ + by + tx] = t[tx][ty + i];
}

// ---------------- output transpose: xtmp[MM][DD] -> per z (16): dst[DD][NN] ----------------
__global__ __launch_bounds__(256) void out_trans_kernel(const float* __restrict__ in,
                                                        float* __restrict__ outA,
                                                        float* __restrict__ outB) {
  __shared__ float t[32][33];
  int z = blockIdx.z;                    // 0..15; <8 => model A, else model B
  int dx = blockIdx.x * 32;              // d tile
  int sy = blockIdx.y * 32;              // seq tile
  int tx = threadIdx.x, ty = threadIdx.y;
  const float* ip = in + (size_t)z * NN * DD;
#pragma unroll
  for (int i = 0; i < 32; i += 8)
    t[ty + i][tx] = ip[(size_t)(sy + ty + i) * DD + dx + tx];
  __syncthreads();
  float* dst = (z < BB) ? (outA + (size_t)z * DD * NN) : (outB + (size_t)(z - BB) * DD * NN);
#pragma unroll
  for (int i = 0; i < 32; i += 8)
    dst[(size_t)(dx + ty + i) * NN + sy + tx] = t[tx][ty + i];
}

// ---------------- bf16 V transpose: V[t][*vstride] (t=b*NN+seq, col h*128+d) -> Vt[bh][d][seq] ----
__global__ __launch_bounds__(256) void vtrans_kernel(const u16* __restrict__ V, int vstride,
                                                     u16* __restrict__ Vt) {
  __shared__ u16 t[32][33];
  int z = blockIdx.z;  // bh, 0..63
  int b = z >> 2, h = z & 3;
  int sx = blockIdx.x * 32;  // seq tile
  int dy = blockIdx.y * 32;  // d tile
  int tx = threadIdx.x, ty = threadIdx.y;
  const u16* ip = V + (size_t)b * NN * vstride + h * 128 + dy;
#pragma unroll
  for (int i = 0; i < 32; i += 8)
    t[ty + i][tx] = ip[(size_t)(sx + ty + i) * vstride + tx];
  __syncthreads();
  u16* op = Vt + ((size_t)z * 128 + dy) * NN + sx;
#pragma unroll
  for (int i = 0; i < 32; i += 8)
    op[(size_t)(ty + i) * NN + tx] = t[tx][ty + i];
}

// ---------------- LayerNorm, wave per row, dual-pointer input (split at RR rows) ----------------
template <int OUTBF>
__global__ __launch_bounds__(256) void ln_kernel(const float* __restrict__ x0,
                                                 const float* __restrict__ x1,
                                                 const float* __restrict__ g,
                                                 const float* __restrict__ bb,
                                                 void* __restrict__ out) {
  int l = threadIdx.x & 63, w = threadIdx.x >> 6;
  size_t row = (size_t)blockIdx.x * 4 + w;
  const float* xr = (row < RR) ? (x0 + row * DD) : (x1 + (row - RR) * DD);
  float4 v0 = *(const float4*)(xr + l * 8);
  float4 v1 = *(const float4*)(xr + l * 8 + 4);
  float sum = v0.x + v0.y + v0.z + v0.w + v1.x + v1.y + v1.z + v1.w;
  float sq = v0.x * v0.x + v0.y * v0.y + v0.z * v0.z + v0.w * v0.w +
             v1.x * v1.x + v1.y * v1.y + v1.z * v1.z + v1.w * v1.w;
#pragma unroll
  for (int o = 1; o < 64; o <<= 1) {
    sum += __shfl_xor(sum, o);
    sq += __shfl_xor(sq, o);
  }
  float mean = sum * (1.0f / DD);
  float var = fmaxf((sq - (float)DD * mean * mean) * (1.0f / (DD - 1)), 0.0f);
  float inv = 1.0f / (sqrtf(var) + 1e-6f);
  float4 g0 = *(const float4*)(g + l * 8), g1 = *(const float4*)(g + l * 8 + 4);
  float4 b0 = *(const float4*)(bb + l * 8), b1 = *(const float4*)(bb + l * 8 + 4);
  float xs[8] = {v0.x, v0.y, v0.z, v0.w, v1.x, v1.y, v1.z, v1.w};
  float gs[8] = {g0.x, g0.y, g0.z, g0.w, g1.x, g1.y, g1.z, g1.w};
  float bs[8] = {b0.x, b0.y, b0.z, b0.w, b1.x, b1.y, b1.z, b1.w};
  float y[8];
#pragma unroll
  for (int j = 0; j < 8; j++) y[j] = (xs[j] - mean) * inv * gs[j] + bs[j];
  if (OUTBF) {
    u16x8 o8;
#pragma unroll
    for (int j = 0; j < 8; j++) o8[j] = f32_to_bf16(y[j]);
    *(u16x8*)((u16*)out + row * DD + l * 8) = o8;
  } else {
    float4 o0 = {y[0], y[1], y[2], y[3]};
    float4 o1 = {y[4], y[5], y[6], y[7]};
    *(float4*)((float*)out + row * DD + l * 8) = o0;
    *(float4*)((float*)out + row * DD + l * 8 + 4) = o1;
  }
}

// ---------------- GEMM: 256x128 tile, 8 waves, BK=64, 3-buf ring, 4-phase interleave ----------
// Each tile = 4 phases: {ds_read subtile + issue prefetch -> barrier -> lgkm0 -> setprio'd
// 8-MFMA cluster -> barrier}. Tile top: counted vmcnt(6) + barrier (never drains mid-loop).
template <bool RELU, bool OUT_BF16, bool HAS_RES>
__global__ __launch_bounds__(512, 2) void gemm_bt(const u16* __restrict__ A, int lda,
                                                  const u16* __restrict__ Bt,
                                                  const float* __restrict__ bias,
                                                  const float* res0, const float* res1,
                                                  void* Cout, int ldc,
                                                  int N2, int Kd) {
  __shared__ u16 sA[3][2048 * 8];  // [buf][chunk 0..7][row 0..255] 16B slots (96KB)
  __shared__ u16 sB[3][1024 * 8];  // [buf][chunk 0..7][row 0..127] (48KB)
  int tid = threadIdx.x;
  int l = tid & 63, w = tid >> 6;
  int wm = (w >> 1) * 64, wn = (w & 1) * 64;
  int m0 = blockIdx.x * 256, n0 = blockIdx.y * 128;
  f32x4 acc[4][4] = {};

  auto stageA2 = [&](int buf, int k0, int half) {  // 2 gl16 (half of A-tile)
#pragma unroll
    for (int is = 0; is < 2; is++) {
      int iss = half * 2 + is;
      int slot = iss * 512 + tid;
      int chunk = slot >> 8, row = slot & 255;
      gl16(&sA[buf][(size_t)(iss * 512 + w * 64) * 8],
           A + (size_t)(m0 + row) * lda + k0 + chunk * 8);
    }
  };
  auto stageB2 = [&](int buf, int k0) {  // 2 gl16 (full B-tile)
#pragma unroll
    for (int is = 0; is < 2; is++) {
      int slot = is * 512 + tid;
      int chunk = slot >> 7, row = slot & 127;
      gl16(&sB[buf][(size_t)(is * 512 + w * 64) * 8],
           Bt + (size_t)(n0 + row) * Kd + k0 + chunk * 8);
    }
  };
  int NT = Kd >> 6;
  stageA2(0, 0, 0); stageA2(0, 0, 1); stageB2(0, 0);
  stageA2(1, 64, 0); stageA2(1, 64, 1); stageB2(1, 64);
  int bi = 0;
  for (int t = 0; t < NT; t++) {
    // tile-t data must be in LDS; tile t+1's 6 loads stay in flight (T4)
    if (t + 1 < NT) asm volatile("s_waitcnt vmcnt(6)" ::: "memory");
    else            asm volatile("s_waitcnt vmcnt(0)" ::: "memory");
    __builtin_amdgcn_s_barrier();
    __builtin_amdgcn_sched_barrier(0);
    int b2 = bi + 2; if (b2 >= 3) b2 -= 3;
    int k2 = (t + 2) * 64;
    bool pre = (t + 2 < NT);
    u16x8 bfr[4][2];
#pragma unroll
    for (int p = 0; p < 4; p++) {
      // ---- phase p: ds_read subtile + issue prefetch slice ----
      if (p == 0) {
#pragma unroll
        for (int j = 0; j < 4; j++)
#pragma unroll
          for (int ks = 0; ks < 2; ks++)
            bfr[j][ks] = *(const u16x8*)&sB[bi][((size_t)(ks * 4 + (l >> 4)) * 128 + wn + j * 16 + (l & 15)) * 8];
      }
      u16x8 afr[2];
#pragma unroll
      for (int ks = 0; ks < 2; ks++)
        afr[ks] = *(const u16x8*)&sA[bi][((size_t)(ks * 4 + (l >> 4)) * 256 + wm + p * 16 + (l & 15)) * 8];
      if (pre) {
        if (p == 0) stageA2(b2, k2, 0);
        else if (p == 1) stageA2(b2, k2, 1);
        else if (p == 2) stageB2(b2, k2);
      }
      __builtin_amdgcn_s_barrier();
      __builtin_amdgcn_sched_barrier(0);
      asm volatile("s_waitcnt lgkmcnt(0)" ::: "memory");
      __builtin_amdgcn_sched_barrier(0);
      __builtin_amdgcn_s_setprio(1);
#pragma unroll
      for (int ks = 0; ks < 2; ks++)
#pragma unroll
        for (int j = 0; j < 4; j++)
          acc[p][j] = mfma16(afr[ks], bfr[j][ks], acc[p][j]);
      __builtin_amdgcn_s_setprio(0);
      if (p < 3) __builtin_amdgcn_s_barrier();
    }
    bi++; if (bi >= 3) bi = 0;
  }
  // ---- epilogue: LDS-transposed, vectorized ----
  __syncthreads();                       // all waves done reading sA/sB
  float* eTw = (float*)&sA[0][0] + w * 1024;  // 4KB per wave (32KB total)
  float4 bias4 = *(const float4*)&bias[n0 + wn + (l & 15) * 4];
#pragma unroll
  for (int i = 0; i < 4; i++) {
#pragma unroll
    for (int j = 0; j < 4; j++)
#pragma unroll
      for (int r = 0; r < 4; r++)
        eTw[((l >> 4) * 4 + r) * 64 + j * 16 + (l & 15)] = acc[i][j][r];
#pragma unroll
    for (int t = 0; t < 4; t++) {
      int row = t * 4 + (l >> 4);        // 0..15 within slab
      int f4 = l & 15;
      float4 v4 = *(float4*)&eTw[row * 64 + f4 * 4];
      int gm = m0 + wm + i * 16 + row;
      int gn = n0 + wn + f4 * 4;
      v4.x += bias4.x; v4.y += bias4.y; v4.z += bias4.z; v4.w += bias4.w;
      if (RELU) {
        v4.x = fmaxf(v4.x, 0.0f); v4.y = fmaxf(v4.y, 0.0f);
        v4.z = fmaxf(v4.z, 0.0f); v4.w = fmaxf(v4.w, 0.0f);
      }
      if (HAS_RES) {
        const float* rp = (gm < RR) ? (res0 + (size_t)gm * DD)
                                    : (res1 + (size_t)(gm - RR) * DD);
        float4 r4 = *(const float4*)&rp[gn];
        v4.x += r4.x; v4.y += r4.y; v4.z += r4.z; v4.w += r4.w;
      }
      if (OUT_BF16) {
        u16x4 o4;
        o4[0] = f32_to_bf16(v4.x); o4[1] = f32_to_bf16(v4.y);
        o4[2] = f32_to_bf16(v4.z); o4[3] = f32_to_bf16(v4.w);
        *(u16x4*)&((u16*)Cout)[(size_t)gm * ldc + gn] = o4;
      } else {
        *(float4*)&((float*)Cout)[(size_t)gm * ldc + gn] = v4;
      }
    }
  }
}

// ---------------- flash attention: 8 waves x 16 q-rows (QBLK=128), KVBLK=64, fixed-max ----------
__global__ __launch_bounds__(512, 4) void attn_kernel(const u16* __restrict__ Q, int qstride,
                                                      const u16* __restrict__ K, int kstride,
                                                      const u16* __restrict__ Vt,
                                                      u16* __restrict__ O, int ostride) {
  __shared__ u16 sK[2][64 * 128];  // [row][dk], byte ^= (row&7)<<4
  __shared__ u16 sV[2][128 * 64];  // [d][k],   byte ^= (d&7)<<4
  __shared__ u16 sP[8][16 * 64];   // per-wave P tile, swizzled
  int tid = threadIdx.x;
  int l = tid & 63, w = tid >> 6;
  int p = blockIdx.x;
  int xcd = p & 7, slot = p >> 3;
  int qb = slot & 7, ghigh = slot >> 3;
  int g = ghigh * 8 + xcd;       // 0..63 = b*4+h
  int b = g >> 2, h = g & 3;
  int q0 = qb * 128 + w * 16;
  int bh = g;

  const u16* Qg = Q + (size_t)b * NN * qstride + h * 128;
  const u16* Kg = K + (size_t)b * NN * kstride + h * 128;
  const u16* Vg = Vt + (size_t)bh * 128 * NN;

  u16x8 qf[4];
#pragma unroll
  for (int c = 0; c < 4; c++)
    qf[c] = *(const u16x8*)(Qg + (size_t)(q0 + (l & 15)) * qstride + c * 32 + (l >> 4) * 8);

  f32x4 oacc[8] = {};
  float psum[4] = {0.0f, 0.0f, 0.0f, 0.0f};
  const float scale = 0.08838834764831843f;  // 1/sqrt(128)

  auto stage = [&](int buf, int k0) {
#pragma unroll
    for (int is = 0; is < 2; is++) {
      int slot2 = is * 512 + tid;
      {  // K tile: 64 rows x 16 slots
        int row = slot2 >> 4, c16 = slot2 & 15;
        int colb = (c16 * 16) ^ ((row & 7) << 4);
        gl16(&sK[buf][(size_t)(is * 512 + w * 64) * 8],
             Kg + (size_t)(k0 + row) * kstride + (colb >> 1));
      }
      {  // Vt tile: 128 rows x 8 slots
        int drow = slot2 >> 3, c16 = slot2 & 7;
        int colb = (c16 * 16) ^ ((drow & 7) << 4);
        gl16(&sV[buf][(size_t)(is * 512 + w * 64) * 8],
             Vg + (size_t)drow * NN + k0 + (colb >> 1));
      }
    }
  };

  stage(0, 0);
  int buf = 0;
  for (int t = 0; t < NN / 64; t++) {
    __syncthreads();
    if (t + 1 < NN / 64) stage(buf ^ 1, (t + 1) * 64);
    // ---- QK^T ----
    f32x4 sc[4] = {};
    __builtin_amdgcn_s_setprio(1);
#pragma unroll
    for (int ks = 0; ks < 4; ks++) {
      int row = ks * 16 + (l & 15);
      int swz = (row & 7) << 4;
#pragma unroll
      for (int c = 0; c < 4; c++) {
        int colb = (c * 64 + (l >> 4) * 16) ^ swz;
        u16x8 kf = *(const u16x8*)&sK[buf][row * 128 + (colb >> 1)];
        sc[ks] = mfma16(qf[c], kf, sc[ks]);
      }
    }
    __builtin_amdgcn_s_setprio(0);
    // ---- fixed-max softmax: p = exp(s*scale), lane-local partial sums ----
#pragma unroll
    for (int r = 0; r < 4; r++) {
      int prow = (l >> 4) * 4 + r;
      int pswz = (prow & 7) << 4;
#pragma unroll
      for (int ks = 0; ks < 4; ks++) {
        float pp = __expf(sc[ks][r] * scale);
        psum[r] += pp;
        int colb = ((ks * 16 + (l & 15)) * 2) ^ pswz;
        sP[w][prow * 64 + (colb >> 1)] = f32_to_bf16(pp);
      }
    }
    // ---- PV ----
    u16x8 pf[2];
#pragma unroll
    for (int kc = 0; kc < 2; kc++) {
      int prow = l & 15;
      int colb = (kc * 64 + (l >> 4) * 16) ^ ((prow & 7) << 4);
      pf[kc] = *(const u16x8*)&sP[w][prow * 64 + (colb >> 1)];
    }
    __builtin_amdgcn_s_setprio(1);
#pragma unroll
    for (int n = 0; n < 8; n++) {
      int drow = n * 16 + (l & 15);
      int swz = (drow & 7) << 4;
#pragma unroll
      for (int kc = 0; kc < 2; kc++) {
        int colb = (kc * 64 + (l >> 4) * 16) ^ swz;
        u16x8 vf = *(const u16x8*)&sV[buf][drow * 64 + (colb >> 1)];
        oacc[n] = mfma16(pf[kc], vf, oacc[n]);
      }
    }
    __builtin_amdgcn_s_setprio(0);
    buf ^= 1;
  }
#pragma unroll
  for (int r = 0; r < 4; r++) {
    psum[r] += __shfl_xor(psum[r], 1);
    psum[r] += __shfl_xor(psum[r], 2);
    psum[r] += __shfl_xor(psum[r], 4);
    psum[r] += __shfl_xor(psum[r], 8);
  }
#pragma unroll
  for (int r = 0; r < 4; r++) {
    float inv = 1.0f / psum[r];
    int grow = q0 + (l >> 4) * 4 + r;
    u16* Op = O + ((size_t)b * NN + grow) * ostride + h * 128 + (l & 15);
#pragma unroll
    for (int n = 0; n < 8; n++) Op[n * 16] = f32_to_bf16(oacc[n][r] * inv);
  }
}

// ---------------- host orchestration ----------------
extern "C" void kernel_launch(void* const* d_in, const int* in_sizes, int n_in,
                              void* d_out, int out_size, void* d_ws, size_t ws_size,
                              hipStream_t stream) {
  const float* src = (const float*)d_in[0];
  const float* tgt = (const float*)d_in[1];
  const float* enc_attn_w = (const float*)d_in[2];
  const float* enc_attn_b = (const float*)d_in[3];
  const float* enc_ff_w1 = (const float*)d_in[4];
  const float* enc_ff_b1 = (const float*)d_in[5];
  const float* enc_ff_w2 = (const float*)d_in[6];
  const float* enc_ff_b2 = (const float*)d_in[7];
  const float* enc_ln_g = (const float*)d_in[8];
  const float* enc_ln_b = (const float*)d_in[9];
  const float* dec_sa_w = (const float*)d_in[10];
  const float* dec_sa_b = (const float*)d_in[11];
  const float* dec_ca_w = (const float*)d_in[12];
  const float* dec_ca_b = (const float*)d_in[13];
  const float* dec_ff_w1 = (const float*)d_in[14];
  const float* dec_ff_b1 = (const float*)d_in[15];
  const float* dec_ff_w2 = (const float*)d_in[16];
  const float* dec_ff_b2 = (const float*)d_in[17];
  const float* dec_ln_g = (const float*)d_in[18];
  const float* dec_ln_b = (const float*)d_in[19];

  // ---- workspace layout ----
  u16* wp = (u16*)d_ws;
  u16* wE = wp;   wp += 4 * DD * DD;   // enc q,k,v,o
  u16* wS = wp;   wp += 4 * DD * DD;   // dec self q,k,v,o
  u16* wC = wp;   wp += 4 * DD * DD;   // dec cross q,k,v,o
  u16* wEff1 = wp; wp += DD * DFFK;
  u16* wEff2 = wp; wp += DD * DFFK;
  u16* wDff1 = wp; wp += DD * DFFK;
  u16* wDff2 = wp; wp += DD * DFFK;
  char* p = (char*)wp;
  float* sT = (float*)p;  p += (size_t)RR * DD * 4;
  float* tT = (float*)p;  p += (size_t)RR * DD * 4;
  float* xb = (float*)p;  p += (size_t)MM * DD * 4;
  u16* hb = (u16*)p;      p += (size_t)MM * DD * 2;
  u16* memb = (u16*)p;    p += (size_t)MM * DD * 2;
  u16* Vt = (u16*)p;      p += (size_t)16 * HH * 128 * NN * 2;
  u16* U = (u16*)p;       p += (size_t)MM * 3 * DD * 2;   // QKV / ffh / xtmp union
  float* xb1 = xb + (size_t)RR * DD;
  float* xtmp = (float*)U;

  // ---- weight conversion ----
  wconv_kernel<<<(4 * DD * DD + 255) / 256, 256, 0, stream>>>(enc_attn_w, wE, DD, DD, 4);
  wconv_kernel<<<(4 * DD * DD + 255) / 256, 256, 0, stream>>>(dec_sa_w, wS, DD, DD, 4);
  wconv_kernel<<<(4 * DD * DD + 255) / 256, 256, 0, stream>>>(dec_ca_w, wC, DD, DD, 4);
  wconv_kernel<<<(DD * DFFK + 255) / 256, 256, 0, stream>>>(enc_ff_w1, wEff1, DD, DFFK, 1);
  wconv_kernel<<<(DD * DFFK + 255) / 256, 256, 0, stream>>>(enc_ff_w2, wEff2, DFFK, DD, 1);
  wconv_kernel<<<(DD * DFFK + 255) / 256, 256, 0, stream>>>(dec_ff_w1, wDff1, DD, DFFK, 1);
  wconv_kernel<<<(DD * DFFK + 255) / 256, 256, 0, stream>>>(dec_ff_w2, wDff2, DFFK, DD, 1);

  // ---- input transposes: [B][D][N] -> [B][N][D] ----
  transpose_kernel<<<dim3(NN / 32, DD / 32, BB), dim3(32, 8), 0, stream>>>(src, sT, DD, NN);
  transpose_kernel<<<dim3(NN / 32, DD / 32, BB), dim3(32, 8), 0, stream>>>(tgt, tT, DD, NN);

  auto ln = [&](const float* x0, const float* x1, const float* g, const float* b,
                void* out, bool bf) {
    if (bf) ln_kernel<1><<<MM / 4, 256, 0, stream>>>(x0, x1, g, b, out);
    else    ln_kernel<0><<<MM / 4, 256, 0, stream>>>(x0, x1, g, b, out);
  };
  auto gemm = [&](const u16* A, int lda, const u16* W, const float* bias,
                  const float* r0, const float* r1, void* out, int ldc,
                  int N2, int K, int mode) {
    dim3 g(MM / 256, N2 / 128);
    if (mode == 0)
      gemm_bt<false, true, false><<<g, 512, 0, stream>>>(A, lda, W, bias, nullptr, nullptr, out, ldc, N2, K);
    else if (mode == 1)
      gemm_bt<true, true, false><<<g, 512, 0, stream>>>(A, lda, W, bias, nullptr, nullptr, out, ldc, N2, K);
    else
      gemm_bt<false, false, true><<<g, 512, 0, stream>>>(A, lda, W, bias, r0, r1, out, ldc, N2, K);
  };
  auto vtrans = [&]() {
    vtrans_kernel<<<dim3(NN / 32, 4, 64), dim3(32, 8), 0, stream>>>(U + 2 * DD, 3 * DD, Vt);
  };
  auto attn = [&]() {
    attn_kernel<<<dim3(512), 512, 0, stream>>>(U, 3 * DD, U + DD, 3 * DD, Vt,
                                               U + 2 * DD, 3 * DD);
  };
  u16* ab = U + 2 * DD;  // attn output lives in the free V slice (lda = 3*DD)

  // ================= batched pass: rows [0,RR)=model A (enc sT, dec tT), [RR,MM)=model B =======
  // ---- encoder ----
  ln(sT, tT, enc_ln_g, enc_ln_b, hb, true);
  gemm(hb, DD, wE, enc_attn_b, nullptr, nullptr, U, 3 * DD, 3 * DD, DD, 0);
  vtrans();
  attn();
  gemm(ab, 3 * DD, wE + 3 * DD * DD, enc_attn_b + 3 * DD, sT, tT, xb, DD, DD, DD, 2);
  ln(xb, xb1, enc_ln_g + DD, enc_ln_b + DD, hb, true);
  gemm(hb, DD, wEff1, enc_ff_b1, nullptr, nullptr, U, DFFK, DFFK, DD, 1);
  gemm(U, DFFK, wEff2, enc_ff_b2, xb, xb1, xb, DD, DD, DFFK, 2);
  ln(xb, xb1, enc_ln_g + 2 * DD, enc_ln_b + 2 * DD, memb, true);
  // ---- decoder self-attn ----
  ln(tT, sT, dec_ln_g, dec_ln_b, hb, true);
  gemm(hb, DD, wS, dec_sa_b, nullptr, nullptr, U, 3 * DD, 3 * DD, DD, 0);
  vtrans();
  attn();
  gemm(ab, 3 * DD, wS + 3 * DD * DD, dec_sa_b + 3 * DD, tT, sT, xb, DD, DD, DD, 2);
  // ---- decoder cross-attn ----
  ln(xb, xb1, dec_ln_g + DD, dec_ln_b + DD, hb, true);
  gemm(hb, DD, wC, dec_ca_b, nullptr, nullptr, U, 3 * DD, DD, DD, 0);               // Q -> col 0
  gemm(memb, DD, wC + DD * DD, dec_ca_b + DD, nullptr, nullptr, U + DD, 3 * DD,
       2 * DD, DD, 0);                                                              // K,V
  vtrans();
  attn();
  gemm(ab, 3 * DD, wC + 3 * DD * DD, dec_ca_b + 3 * DD, xb, xb1, xb, DD, DD, DD, 2);
  // ---- decoder FFN ----
  ln(xb, xb1, dec_ln_g + 2 * DD, dec_ln_b + 2 * DD, hb, true);
  gemm(hb, DD, wDff1, dec_ff_b1, nullptr, nullptr, U, DFFK, DFFK, DD, 1);
  gemm(U, DFFK, wDff2, dec_ff_b2, xb, xb1, xb, DD, DD, DFFK, 2);
  ln(xb, xb1, dec_ln_g + 3 * DD, dec_ln_b + 3 * DD, xtmp, false);
  // ---- output transpose: model A -> tgt_embedding (2nd half), model B -> src_embedding ----
  float* out_f = (float*)d_out;
  out_trans_kernel<<<dim3(DD / 32, NN / 32, 16), dim3(32, 8), 0, stream>>>(
      xtmp, out_f + (size_t)RR * DD, out_f);
}

// Round 12
// 670.328 us; speedup vs baseline: 1.0252x; 1.0252x over previous
//
#include <hip/hip_runtime.h>

#define BB 8
#define NN 1024
#define DD 512
#define DFFK 1024
#define HH 4
#define RR (BB * NN)     // 8192 rows per model
#define MM (2 * RR)      // 16384 combined rows

typedef unsigned short u16;
typedef u16 u16x8 __attribute__((ext_vector_type(8)));
typedef u16 u16x4 __attribute__((ext_vector_type(4)));
typedef float f32x4 __attribute__((ext_vector_type(4)));
typedef __bf16 bf16x8 __attribute__((ext_vector_type(8)));

__device__ __forceinline__ u16 f32_to_bf16(float f) {
  unsigned int u = __builtin_bit_cast(unsigned int, f);
  unsigned int r = u + 0x7FFFu + ((u >> 16) & 1u);
  return (u16)(r >> 16);
}

__device__ __forceinline__ f32x4 mfma16(u16x8 a, u16x8 b, f32x4 c) {
  return __builtin_amdgcn_mfma_f32_16x16x32_bf16(
      __builtin_bit_cast(bf16x8, a), __builtin_bit_cast(bf16x8, b), c, 0, 0, 0);
}

__device__ __forceinline__ void gl16(u16* lds, const u16* g) {
  __builtin_amdgcn_global_load_lds(
      (const __attribute__((address_space(1))) unsigned int*)g,
      (__attribute__((address_space(3))) unsigned int*)lds, 16, 0, 0);
}

// ---------------- weight convert: nmat matrices W[K][N2] f32 -> Wt[N2][K] bf16 ----------------
__global__ __launch_bounds__(256) void wconv_kernel(const float* __restrict__ W,
                                                    u16* __restrict__ Wt, int K, int N2, int nmat) {
  int idx = blockIdx.x * 256 + threadIdx.x;
  if (idx >= nmat * K * N2) return;
  int mat = idx / (K * N2), rem = idx % (K * N2);
  int k = rem % K, n = rem / K;
  Wt[(size_t)mat * K * N2 + (size_t)n * K + k] =
      f32_to_bf16(W[(size_t)mat * K * N2 + (size_t)k * N2 + n]);
}

// ---------------- input transpose: per batch z, in[R_][C_] -> out[C_][R_] ----------------
__global__ __launch_bounds__(256) void transpose_kernel(const float* __restrict__ in,
                                                        float* __restrict__ out, int R_, int C_) {
  __shared__ float t[32][33];
  int bx = blockIdx.x * 32, by = blockIdx.y * 32;
  size_t zoff = (size_t)blockIdx.z * R_ * C_;
  const float* ip = in + zoff;
  float* op = out + zoff;
  int tx = threadIdx.x, ty = threadIdx.y;
#pragma unroll
  for (int i = 0; i < 32; i += 8)
    t[ty + i][tx] = ip[(size_t)(by + ty + i) * C_ + bx + tx];
  __syncthreads();
#pragma unroll
  for (int i = 0; i < 32; i += 8)
    op[(size_t)(bx + ty + i) * R_ + by + tx] = t[tx][ty + i];
}

// ---------------- output transpose: xtmp[MM][DD] -> per z (16): dst[DD][NN] ----------------
__global__ __launch_bounds__(256) void out_trans_kernel(const float* __restrict__ in,
                                                        float* __restrict__ outA,
                                                        float* __restrict__ outB) {
  __shared__ float t[32][33];
  int z = blockIdx.z;                    // 0..15; <8 => model A, else model B
  int dx = blockIdx.x * 32;              // d tile
  int sy = blockIdx.y * 32;              // seq tile
  int tx = threadIdx.x, ty = threadIdx.y;
  const float* ip = in + (size_t)z * NN * DD;
#pragma unroll
  for (int i = 0; i < 32; i += 8)
    t[ty + i][tx] = ip[(size_t)(sy + ty + i) * DD + dx + tx];
  __syncthreads();
  float* dst = (z < BB) ? (outA + (size_t)z * DD * NN) : (outB + (size_t)(z - BB) * DD * NN);
#pragma unroll
  for (int i = 0; i < 32; i += 8)
    dst[(size_t)(dx + ty + i) * NN + sy + tx] = t[tx][ty + i];
}

// ---------------- bf16 V transpose: V[t][*vstride] (t=b*NN+seq, col h*128+d) -> Vt[bh][d][seq] ----
__global__ __launch_bounds__(256) void vtrans_kernel(const u16* __restrict__ V, int vstride,
                                                     u16* __restrict__ Vt) {
  __shared__ u16 t[32][33];
  int z = blockIdx.z;  // bh, 0..63
  int b = z >> 2, h = z & 3;
  int sx = blockIdx.x * 32;  // seq tile
  int dy = blockIdx.y * 32;  // d tile
  int tx = threadIdx.x, ty = threadIdx.y;
  const u16* ip = V + (size_t)b * NN * vstride + h * 128 + dy;
#pragma unroll
  for (int i = 0; i < 32; i += 8)
    t[ty + i][tx] = ip[(size_t)(sx + ty + i) * vstride + tx];
  __syncthreads();
  u16* op = Vt + ((size_t)z * 128 + dy) * NN + sx;
#pragma unroll
  for (int i = 0; i < 32; i += 8)
    op[(size_t)(ty + i) * NN + tx] = t[tx][ty + i];
}

// ---------------- LayerNorm, wave per row, dual-pointer input (split at RR rows) ----------------
template <int OUTBF>
__global__ __launch_bounds__(256) void ln_kernel(const float* __restrict__ x0,
                                                 const float* __restrict__ x1,
                                                 const float* __restrict__ g,
                                                 const float* __restrict__ bb,
                                                 void* __restrict__ out) {
  int l = threadIdx.x & 63, w = threadIdx.x >> 6;
  size_t row = (size_t)blockIdx.x * 4 + w;
  const float* xr = (row < RR) ? (x0 + row * DD) : (x1 + (row - RR) * DD);
  float4 v0 = *(const float4*)(xr + l * 8);
  float4 v1 = *(const float4*)(xr + l * 8 + 4);
  float sum = v0.x + v0.y + v0.z + v0.w + v1.x + v1.y + v1.z + v1.w;
  float sq = v0.x * v0.x + v0.y * v0.y + v0.z * v0.z + v0.w * v0.w +
             v1.x * v1.x + v1.y * v1.y + v1.z * v1.z + v1.w * v1.w;
#pragma unroll
  for (int o = 1; o < 64; o <<= 1) {
    sum += __shfl_xor(sum, o);
    sq += __shfl_xor(sq, o);
  }
  float mean = sum * (1.0f / DD);
  float var = fmaxf((sq - (float)DD * mean * mean) * (1.0f / (DD - 1)), 0.0f);
  float inv = 1.0f / (sqrtf(var) + 1e-6f);
  float4 g0 = *(const float4*)(g + l * 8), g1 = *(const float4*)(g + l * 8 + 4);
  float4 b0 = *(const float4*)(bb + l * 8), b1 = *(const float4*)(bb + l * 8 + 4);
  float xs[8] = {v0.x, v0.y, v0.z, v0.w, v1.x, v1.y, v1.z, v1.w};
  float gs[8] = {g0.x, g0.y, g0.z, g0.w, g1.x, g1.y, g1.z, g1.w};
  float bs[8] = {b0.x, b0.y, b0.z, b0.w, b1.x, b1.y, b1.z, b1.w};
  float y[8];
#pragma unroll
  for (int j = 0; j < 8; j++) y[j] = (xs[j] - mean) * inv * gs[j] + bs[j];
  if (OUTBF) {
    u16x8 o8;
#pragma unroll
    for (int j = 0; j < 8; j++) o8[j] = f32_to_bf16(y[j]);
    *(u16x8*)((u16*)out + row * DD + l * 8) = o8;
  } else {
    float4 o0 = {y[0], y[1], y[2], y[3]};
    float4 o1 = {y[4], y[5], y[6], y[7]};
    *(float4*)((float*)out + row * DD + l * 8) = o0;
    *(float4*)((float*)out + row * DD + l * 8 + 4) = o1;
  }
}

// ---------------- GEMM (round-7 proven): 256x128, 8 waves, BK=64, 3-buf ring, vmcnt(6) ------
// 1D grid with XCD-aware bijective swizzle (nwg % 8 == 0 for all our shapes): each XCD gets
// a contiguous chunk decoded bx-major, so the gy blocks sharing an A-stripe share an L2.
template <bool RELU, bool OUT_BF16, bool HAS_RES>
__global__ __launch_bounds__(512, 2) void gemm_bt(const u16* __restrict__ A, int lda,
                                                  const u16* __restrict__ Bt,
                                                  const float* __restrict__ bias,
                                                  const float* res0, const float* res1,
                                                  void* Cout, int ldc,
                                                  int N2, int Kd, int gy) {
  __shared__ u16 sA[3][2048 * 8];  // [buf][chunk 0..7][row 0..255] 16B slots (96KB)
  __shared__ u16 sB[3][1024 * 8];  // [buf][chunk 0..7][row 0..127] (48KB)
  int tid = threadIdx.x;
  int l = tid & 63, w = tid >> 6;
  int wm = (w >> 1) * 64, wn = (w & 1) * 64;
  // XCD swizzle: g -> wg (chunked), then bx-major decode
  int nwg = gridDim.x;
  int chunkn = nwg >> 3;
  int g = blockIdx.x;
  int wg = (g & 7) * chunkn + (g >> 3);
  int bx = wg / gy, by = wg - bx * gy;
  int m0 = bx * 256, n0 = by * 128;
  f32x4 acc[4][4] = {};

  auto stageA = [&](int buf, int k0) {
#pragma unroll
    for (int is = 0; is < 4; is++) {
      int slot = is * 512 + tid;
      int chunk = slot >> 8, row = slot & 255;
      gl16(&sA[buf][(size_t)(is * 512 + w * 64) * 8],
           A + (size_t)(m0 + row) * lda + k0 + chunk * 8);
    }
  };
  auto stageB = [&](int buf, int k0) {
#pragma unroll
    for (int is = 0; is < 2; is++) {
      int slot = is * 512 + tid;
      int chunk = slot >> 7, row = slot & 127;
      gl16(&sB[buf][(size_t)(is * 512 + w * 64) * 8],
           Bt + (size_t)(n0 + row) * Kd + k0 + chunk * 8);
    }
  };
  int NT = Kd >> 6;
  stageA(0, 0); stageB(0, 0);
  stageA(1, 64); stageB(1, 64);
  int bi = 0;
  for (int t = 0; t < NT; t++) {
    if (t + 1 < NT) asm volatile("s_waitcnt vmcnt(6)" ::: "memory");
    else            asm volatile("s_waitcnt vmcnt(0)" ::: "memory");
    __builtin_amdgcn_s_barrier();
    __builtin_amdgcn_sched_barrier(0);
    int b2 = bi + 2; if (b2 >= 3) b2 -= 3;
    int k2 = (t + 2) * 64;
    // ---- phase A: read all B-frags (cached for both phases) + A rows 0..31; prefetch A ----
    u16x8 bfr[4][2], afr[2][2];
#pragma unroll
    for (int j = 0; j < 4; j++)
#pragma unroll
      for (int ks = 0; ks < 2; ks++)
        bfr[j][ks] = *(const u16x8*)&sB[bi][((size_t)(ks * 4 + (l >> 4)) * 128 + wn + j * 16 + (l & 15)) * 8];
#pragma unroll
    for (int i = 0; i < 2; i++)
#pragma unroll
      for (int ks = 0; ks < 2; ks++)
        afr[i][ks] = *(const u16x8*)&sA[bi][((size_t)(ks * 4 + (l >> 4)) * 256 + wm + i * 16 + (l & 15)) * 8];
    if (t + 2 < NT) stageA(b2, k2);
    __builtin_amdgcn_s_setprio(1);
#pragma unroll
    for (int ks = 0; ks < 2; ks++)
#pragma unroll
      for (int i = 0; i < 2; i++)
#pragma unroll
        for (int j = 0; j < 4; j++)
          acc[i][j] = mfma16(afr[i][ks], bfr[j][ks], acc[i][j]);
    __builtin_amdgcn_s_setprio(0);
    __builtin_amdgcn_s_barrier();
    // ---- phase B: A rows 32..63; prefetch B ----
    u16x8 afr2[2][2];
#pragma unroll
    for (int i = 0; i < 2; i++)
#pragma unroll
      for (int ks = 0; ks < 2; ks++)
        afr2[i][ks] = *(const u16x8*)&sA[bi][((size_t)(ks * 4 + (l >> 4)) * 256 + wm + (i + 2) * 16 + (l & 15)) * 8];
    if (t + 2 < NT) stageB(b2, k2);
    __builtin_amdgcn_s_setprio(1);
#pragma unroll
    for (int ks = 0; ks < 2; ks++)
#pragma unroll
      for (int i = 0; i < 2; i++)
#pragma unroll
        for (int j = 0; j < 4; j++)
          acc[i + 2][j] = mfma16(afr2[i][ks], bfr[j][ks], acc[i + 2][j]);
    __builtin_amdgcn_s_setprio(0);
    bi++; if (bi >= 3) bi = 0;
  }
  // ---- epilogue: LDS-transposed, vectorized ----
  __syncthreads();
  float* eTw = (float*)&sA[0][0] + w * 1024;
  float4 bias4 = *(const float4*)&bias[n0 + wn + (l & 15) * 4];
#pragma unroll
  for (int i = 0; i < 4; i++) {
#pragma unroll
    for (int j = 0; j < 4; j++)
#pragma unroll
      for (int r = 0; r < 4; r++)
        eTw[((l >> 4) * 4 + r) * 64 + j * 16 + (l & 15)] = acc[i][j][r];
#pragma unroll
    for (int t = 0; t < 4; t++) {
      int row = t * 4 + (l >> 4);
      int f4 = l & 15;
      float4 v4 = *(float4*)&eTw[row * 64 + f4 * 4];
      int gm = m0 + wm + i * 16 + row;
      int gn = n0 + wn + f4 * 4;
      v4.x += bias4.x; v4.y += bias4.y; v4.z += bias4.z; v4.w += bias4.w;
      if (RELU) {
        v4.x = fmaxf(v4.x, 0.0f); v4.y = fmaxf(v4.y, 0.0f);
        v4.z = fmaxf(v4.z, 0.0f); v4.w = fmaxf(v4.w, 0.0f);
      }
      if (HAS_RES) {
        const float* rp = (gm < RR) ? (res0 + (size_t)gm * DD)
                                    : (res1 + (size_t)(gm - RR) * DD);
        float4 r4 = *(const float4*)&rp[gn];
        v4.x += r4.x; v4.y += r4.y; v4.z += r4.z; v4.w += r4.w;
      }
      if (OUT_BF16) {
        u16x4 o4;
        o4[0] = f32_to_bf16(v4.x); o4[1] = f32_to_bf16(v4.y);
        o4[2] = f32_to_bf16(v4.z); o4[3] = f32_to_bf16(v4.w);
        *(u16x4*)&((u16*)Cout)[(size_t)gm * ldc + gn] = o4;
      } else {
        *(float4*)&((float*)Cout)[(size_t)gm * ldc + gn] = v4;
      }
    }
  }
}

// ---------------- flash attention: 8 waves x 16 q-rows (QBLK=128), KVBLK=64, fixed-max ----------
__global__ __launch_bounds__(512, 4) void attn_kernel(const u16* __restrict__ Q, int qstride,
                                                      const u16* __restrict__ K, int kstride,
                                                      const u16* __restrict__ Vt,
                                                      u16* __restrict__ O, int ostride) {
  __shared__ u16 sK[2][64 * 128];  // [row][dk], byte ^= (row&7)<<4
  __shared__ u16 sV[2][128 * 64];  // [d][k],   byte ^= (d&7)<<4
  __shared__ u16 sP[8][16 * 64];   // per-wave P tile, swizzled
  int tid = threadIdx.x;
  int l = tid & 63, w = tid >> 6;
  int p = blockIdx.x;
  int xcd = p & 7, slot = p >> 3;
  int qb = slot & 7, ghigh = slot >> 3;
  int g = ghigh * 8 + xcd;       // 0..63 = b*4+h
  int b = g >> 2, h = g & 3;
  int q0 = qb * 128 + w * 16;
  int bh = g;

  const u16* Qg = Q + (size_t)b * NN * qstride + h * 128;
  const u16* Kg = K + (size_t)b * NN * kstride + h * 128;
  const u16* Vg = Vt + (size_t)bh * 128 * NN;

  u16x8 qf[4];
#pragma unroll
  for (int c = 0; c < 4; c++)
    qf[c] = *(const u16x8*)(Qg + (size_t)(q0 + (l & 15)) * qstride + c * 32 + (l >> 4) * 8);

  f32x4 oacc[8] = {};
  float psum[4] = {0.0f, 0.0f, 0.0f, 0.0f};
  const float scale = 0.08838834764831843f;  // 1/sqrt(128)

  auto stage = [&](int buf, int k0) {
#pragma unroll
    for (int is = 0; is < 2; is++) {
      int slot2 = is * 512 + tid;
      {  // K tile: 64 rows x 16 slots
        int row = slot2 >> 4, c16 = slot2 & 15;
        int colb = (c16 * 16) ^ ((row & 7) << 4);
        gl16(&sK[buf][(size_t)(is * 512 + w * 64) * 8],
             Kg + (size_t)(k0 + row) * kstride + (colb >> 1));
      }
      {  // Vt tile: 128 rows x 8 slots
        int drow = slot2 >> 3, c16 = slot2 & 7;
        int colb = (c16 * 16) ^ ((drow & 7) << 4);
        gl16(&sV[buf][(size_t)(is * 512 + w * 64) * 8],
             Vg + (size_t)drow * NN + k0 + (colb >> 1));
      }
    }
  };

  stage(0, 0);
  int buf = 0;
  for (int t = 0; t < NN / 64; t++) {
    __syncthreads();
    if (t + 1 < NN / 64) stage(buf ^ 1, (t + 1) * 64);
    // ---- QK^T ----
    f32x4 sc[4] = {};
    __builtin_amdgcn_s_setprio(1);
#pragma unroll
    for (int ks = 0; ks < 4; ks++) {
      int row = ks * 16 + (l & 15);
      int swz = (row & 7) << 4;
#pragma unroll
      for (int c = 0; c < 4; c++) {
        int colb = (c * 64 + (l >> 4) * 16) ^ swz;
        u16x8 kf = *(const u16x8*)&sK[buf][row * 128 + (colb >> 1)];
        sc[ks] = mfma16(qf[c], kf, sc[ks]);
      }
    }
    __builtin_amdgcn_s_setprio(0);
    // ---- fixed-max softmax: p = exp(s*scale), lane-local partial sums ----
#pragma unroll
    for (int r = 0; r < 4; r++) {
      int prow = (l >> 4) * 4 + r;
      int pswz = (prow & 7) << 4;
#pragma unroll
      for (int ks = 0; ks < 4; ks++) {
        float pp = __expf(sc[ks][r] * scale);
        psum[r] += pp;
        int colb = ((ks * 16 + (l & 15)) * 2) ^ pswz;
        sP[w][prow * 64 + (colb >> 1)] = f32_to_bf16(pp);
      }
    }
    // ---- PV ----
    u16x8 pf[2];
#pragma unroll
    for (int kc = 0; kc < 2; kc++) {
      int prow = l & 15;
      int colb = (kc * 64 + (l >> 4) * 16) ^ ((prow & 7) << 4);
      pf[kc] = *(const u16x8*)&sP[w][prow * 64 + (colb >> 1)];
    }
    __builtin_amdgcn_s_setprio(1);
#pragma unroll
    for (int n = 0; n < 8; n++) {
      int drow = n * 16 + (l & 15);
      int swz = (drow & 7) << 4;
#pragma unroll
      for (int kc = 0; kc < 2; kc++) {
        int colb = (kc * 64 + (l >> 4) * 16) ^ swz;
        u16x8 vf = *(const u16x8*)&sV[buf][drow * 64 + (colb >> 1)];
        oacc[n] = mfma16(pf[kc], vf, oacc[n]);
      }
    }
    __builtin_amdgcn_s_setprio(0);
    buf ^= 1;
  }
#pragma unroll
  for (int r = 0; r < 4; r++) {
    psum[r] += __shfl_xor(psum[r], 1);
    psum[r] += __shfl_xor(psum[r], 2);
    psum[r] += __shfl_xor(psum[r], 4);
    psum[r] += __shfl_xor(psum[r], 8);
  }
#pragma unroll
  for (int r = 0; r < 4; r++) {
    float inv = 1.0f / psum[r];
    int grow = q0 + (l >> 4) * 4 + r;
    u16* Op = O + ((size_t)b * NN + grow) * ostride + h * 128 + (l & 15);
#pragma unroll
    for (int n = 0; n < 8; n++) Op[n * 16] = f32_to_bf16(oacc[n][r] * inv);
  }
}

// ---------------- host orchestration ----------------
extern "C" void kernel_launch(void* const* d_in, const int* in_sizes, int n_in,
                              void* d_out, int out_size, void* d_ws, size_t ws_size,
                              hipStream_t stream) {
  const float* src = (const float*)d_in[0];
  const float* tgt = (const float*)d_in[1];
  const float* enc_attn_w = (const float*)d_in[2];
  const float* enc_attn_b = (const float*)d_in[3];
  const float* enc_ff_w1 = (const float*)d_in[4];
  const float* enc_ff_b1 = (const float*)d_in[5];
  const float* enc_ff_w2 = (const float*)d_in[6];
  const float* enc_ff_b2 = (const float*)d_in[7];
  const float* enc_ln_g = (const float*)d_in[8];
  const float* enc_ln_b = (const float*)d_in[9];
  const float* dec_sa_w = (const float*)d_in[10];
  const float* dec_sa_b = (const float*)d_in[11];
  const float* dec_ca_w = (const float*)d_in[12];
  const float* dec_ca_b = (const float*)d_in[13];
  const float* dec_ff_w1 = (const float*)d_in[14];
  const float* dec_ff_b1 = (const float*)d_in[15];
  const float* dec_ff_w2 = (const float*)d_in[16];
  const float* dec_ff_b2 = (const float*)d_in[17];
  const float* dec_ln_g = (const float*)d_in[18];
  const float* dec_ln_b = (const float*)d_in[19];

  // ---- workspace layout ----
  u16* wp = (u16*)d_ws;
  u16* wE = wp;   wp += 4 * DD * DD;   // enc q,k,v,o
  u16* wS = wp;   wp += 4 * DD * DD;   // dec self q,k,v,o
  u16* wC = wp;   wp += 4 * DD * DD;   // dec cross q,k,v,o
  u16* wEff1 = wp; wp += DD * DFFK;
  u16* wEff2 = wp; wp += DD * DFFK;
  u16* wDff1 = wp; wp += DD * DFFK;
  u16* wDff2 = wp; wp += DD * DFFK;
  char* p = (char*)wp;
  float* sT = (float*)p;  p += (size_t)RR * DD * 4;
  float* tT = (float*)p;  p += (size_t)RR * DD * 4;
  float* xb = (float*)p;  p += (size_t)MM * DD * 4;
  u16* hb = (u16*)p;      p += (size_t)MM * DD * 2;
  u16* memb = (u16*)p;    p += (size_t)MM * DD * 2;
  u16* Vt = (u16*)p;      p += (size_t)16 * HH * 128 * NN * 2;
  u16* U = (u16*)p;       p += (size_t)MM * 3 * DD * 2;   // QKV / ffh / xtmp union
  float* xb1 = xb + (size_t)RR * DD;
  float* xtmp = (float*)U;

  // ---- weight conversion ----
  wconv_kernel<<<(4 * DD * DD + 255) / 256, 256, 0, stream>>>(enc_attn_w, wE, DD, DD, 4);
  wconv_kernel<<<(4 * DD * DD + 255) / 256, 256, 0, stream>>>(dec_sa_w, wS, DD, DD, 4);
  wconv_kernel<<<(4 * DD * DD + 255) / 256, 256, 0, stream>>>(dec_ca_w, wC, DD, DD, 4);
  wconv_kernel<<<(DD * DFFK + 255) / 256, 256, 0, stream>>>(enc_ff_w1, wEff1, DD, DFFK, 1);
  wconv_kernel<<<(DD * DFFK + 255) / 256, 256, 0, stream>>>(enc_ff_w2, wEff2, DFFK, DD, 1);
  wconv_kernel<<<(DD * DFFK + 255) / 256, 256, 0, stream>>>(dec_ff_w1, wDff1, DD, DFFK, 1);
  wconv_kernel<<<(DD * DFFK + 255) / 256, 256, 0, stream>>>(dec_ff_w2, wDff2, DFFK, DD, 1);

  // ---- input transposes: [B][D][N] -> [B][N][D] ----
  transpose_kernel<<<dim3(NN / 32, DD / 32, BB), dim3(32, 8), 0, stream>>>(src, sT, DD, NN);
  transpose_kernel<<<dim3(NN / 32, DD / 32, BB), dim3(32, 8), 0, stream>>>(tgt, tT, DD, NN);

  auto ln = [&](const float* x0, const float* x1, const float* g, const float* b,
                void* out, bool bf) {
    if (bf) ln_kernel<1><<<MM / 4, 256, 0, stream>>>(x0, x1, g, b, out);
    else    ln_kernel<0><<<MM / 4, 256, 0, stream>>>(x0, x1, g, b, out);
  };
  auto gemm = [&](const u16* A, int lda, const u16* W, const float* bias,
                  const float* r0, const float* r1, void* out, int ldc,
                  int N2, int K, int mode) {
    int gy = N2 / 128;
    dim3 g((MM / 256) * gy);
    if (mode == 0)
      gemm_bt<false, true, false><<<g, 512, 0, stream>>>(A, lda, W, bias, nullptr, nullptr, out, ldc, N2, K, gy);
    else if (mode == 1)
      gemm_bt<true, true, false><<<g, 512, 0, stream>>>(A, lda, W, bias, nullptr, nullptr, out, ldc, N2, K, gy);
    else
      gemm_bt<false, false, true><<<g, 512, 0, stream>>>(A, lda, W, bias, r0, r1, out, ldc, N2, K, gy);
  };
  auto vtrans = [&]() {
    vtrans_kernel<<<dim3(NN / 32, 4, 64), dim3(32, 8), 0, stream>>>(U + 2 * DD, 3 * DD, Vt);
  };
  auto attn = [&]() {
    attn_kernel<<<dim3(512), 512, 0, stream>>>(U, 3 * DD, U + DD, 3 * DD, Vt,
                                               U + 2 * DD, 3 * DD);
  };
  u16* ab = U + 2 * DD;  // attn output lives in the free V slice (lda = 3*DD)

  // ================= batched pass: rows [0,RR)=model A (enc sT, dec tT), [RR,MM)=model B =======
  // ---- encoder ----
  ln(sT, tT, enc_ln_g, enc_ln_b, hb, true);
  gemm(hb, DD, wE, enc_attn_b, nullptr, nullptr, U, 3 * DD, 3 * DD, DD, 0);
  vtrans();
  attn();
  gemm(ab, 3 * DD, wE + 3 * DD * DD, enc_attn_b + 3 * DD, sT, tT, xb, DD, DD, DD, 2);
  ln(xb, xb1, enc_ln_g + DD, enc_ln_b + DD, hb, true);
  gemm(hb, DD, wEff1, enc_ff_b1, nullptr, nullptr, U, DFFK, DFFK, DD, 1);
  gemm(U, DFFK, wEff2, enc_ff_b2, xb, xb1, xb, DD, DD, DFFK, 2);
  ln(xb, xb1, enc_ln_g + 2 * DD, enc_ln_b + 2 * DD, memb, true);
  // ---- decoder self-attn ----
  ln(tT, sT, dec_ln_g, dec_ln_b, hb, true);
  gemm(hb, DD, wS, dec_sa_b, nullptr, nullptr, U, 3 * DD, 3 * DD, DD, 0);
  vtrans();
  attn();
  gemm(ab, 3 * DD, wS + 3 * DD * DD, dec_sa_b + 3 * DD, tT, sT, xb, DD, DD, DD, 2);
  // ---- decoder cross-attn ----
  ln(xb, xb1, dec_ln_g + DD, dec_ln_b + DD, hb, true);
  gemm(hb, DD, wC, dec_ca_b, nullptr, nullptr, U, 3 * DD, DD, DD, 0);               // Q -> col 0
  gemm(memb, DD, wC + DD * DD, dec_ca_b + DD, nullptr, nullptr, U + DD, 3 * DD,
       2 * DD, DD, 0);                                                              // K,V
  vtrans();
  attn();
  gemm(ab, 3 * DD, wC + 3 * DD * DD, dec_ca_b + 3 * DD, xb, xb1, xb, DD, DD, DD, 2);
  // ---- decoder FFN ----
  ln(xb, xb1, dec_ln_g + 2 * DD, dec_ln_b + 2 * DD, hb, true);
  gemm(hb, DD, wDff1, dec_ff_b1, nullptr, nullptr, U, DFFK, DFFK, DD, 1);
  gemm(U, DFFK, wDff2, dec_ff_b2, xb, xb1, xb, DD, DD, DFFK, 2);
  ln(xb, xb1, dec_ln_g + 3 * DD, dec_ln_b + 3 * DD, xtmp, false);
  // ---- output transpose: model A -> tgt_embedding (2nd half), model B -> src_embedding ----
  float* out_f = (float*)d_out;
  out_trans_kernel<<<dim3(DD / 32, NN / 32, 16), dim3(32, 8), 0, stream>>>(
      xtmp, out_f + (size_t)RR * DD, out_f);
}

// Round 13
// 651.999 us; speedup vs baseline: 1.0541x; 1.0281x over previous
//
#include <hip/hip_runtime.h>

#define BB 8
#define NN 1024
#define DD 512
#define DFFK 1024
#define HH 4
#define RR (BB * NN)     // 8192 rows per model
#define MM (2 * RR)      // 16384 combined rows

typedef unsigned short u16;
typedef u16 u16x8 __attribute__((ext_vector_type(8)));
typedef u16 u16x4 __attribute__((ext_vector_type(4)));
typedef float f32x4 __attribute__((ext_vector_type(4)));
typedef __bf16 bf16x8 __attribute__((ext_vector_type(8)));

__device__ __forceinline__ u16 f32_to_bf16(float f) {
  unsigned int u = __builtin_bit_cast(unsigned int, f);
  unsigned int r = u + 0x7FFFu + ((u >> 16) & 1u);
  return (u16)(r >> 16);
}

__device__ __forceinline__ float b2f(u16 u) {
  unsigned int v = ((unsigned int)u) << 16;
  return __builtin_bit_cast(float, v);
}

__device__ __forceinline__ f32x4 mfma16(u16x8 a, u16x8 b, f32x4 c) {
  return __builtin_amdgcn_mfma_f32_16x16x32_bf16(
      __builtin_bit_cast(bf16x8, a), __builtin_bit_cast(bf16x8, b), c, 0, 0, 0);
}

__device__ __forceinline__ void gl16(u16* lds, const u16* g) {
  __builtin_amdgcn_global_load_lds(
      (const __attribute__((address_space(1))) unsigned int*)g,
      (__attribute__((address_space(3))) unsigned int*)lds, 16, 0, 0);
}

// ---------------- weight convert: nmat matrices W[K][N2] f32 -> Wt[N2][K] bf16 ----------------
__global__ __launch_bounds__(256) void wconv_kernel(const float* __restrict__ W,
                                                    u16* __restrict__ Wt, int K, int N2, int nmat) {
  int idx = blockIdx.x * 256 + threadIdx.x;
  if (idx >= nmat * K * N2) return;
  int mat = idx / (K * N2), rem = idx % (K * N2);
  int k = rem % K, n = rem / K;
  Wt[(size_t)mat * K * N2 + (size_t)n * K + k] =
      f32_to_bf16(W[(size_t)mat * K * N2 + (size_t)k * N2 + n]);
}

// ---------------- input transpose: per batch z, in[R_][C_] -> out[C_][R_] ----------------
__global__ __launch_bounds__(256) void transpose_kernel(const float* __restrict__ in,
                                                        float* __restrict__ out, int R_, int C_) {
  __shared__ float t[32][33];
  int bx = blockIdx.x * 32, by = blockIdx.y * 32;
  size_t zoff = (size_t)blockIdx.z * R_ * C_;
  const float* ip = in + zoff;
  float* op = out + zoff;
  int tx = threadIdx.x, ty = threadIdx.y;
#pragma unroll
  for (int i = 0; i < 32; i += 8)
    t[ty + i][tx] = ip[(size_t)(by + ty + i) * C_ + bx + tx];
  __syncthreads();
#pragma unroll
  for (int i = 0; i < 32; i += 8)
    op[(size_t)(bx + ty + i) * R_ + by + tx] = t[tx][ty + i];
}

// ---------------- output transpose: xtmp[MM][DD] -> per z (16): dst[DD][NN] ----------------
__global__ __launch_bounds__(256) void out_trans_kernel(const float* __restrict__ in,
                                                        float* __restrict__ outA,
                                                        float* __restrict__ outB) {
  __shared__ float t[32][33];
  int z = blockIdx.z;
  int dx = blockIdx.x * 32;
  int sy = blockIdx.y * 32;
  int tx = threadIdx.x, ty = threadIdx.y;
  const float* ip = in + (size_t)z * NN * DD;
#pragma unroll
  for (int i = 0; i < 32; i += 8)
    t[ty + i][tx] = ip[(size_t)(sy + ty + i) * DD + dx + tx];
  __syncthreads();
  float* dst = (z < BB) ? (outA + (size_t)z * DD * NN) : (outB + (size_t)(z - BB) * DD * NN);
#pragma unroll
  for (int i = 0; i < 32; i += 8)
    dst[(size_t)(dx + ty + i) * NN + sy + tx] = t[tx][ty + i];
}

// ---------------- bf16 V transpose: V[t][*vstride] -> Vt[bh][d][seq] ----------------
__global__ __launch_bounds__(256) void vtrans_kernel(const u16* __restrict__ V, int vstride,
                                                     u16* __restrict__ Vt) {
  __shared__ u16 t[32][33];
  int z = blockIdx.z;
  int b = z >> 2, h = z & 3;
  int sx = blockIdx.x * 32;
  int dy = blockIdx.y * 32;
  int tx = threadIdx.x, ty = threadIdx.y;
  const u16* ip = V + (size_t)b * NN * vstride + h * 128 + dy;
#pragma unroll
  for (int i = 0; i < 32; i += 8)
    t[ty + i][tx] = ip[(size_t)(sx + ty + i) * vstride + tx];
  __syncthreads();
  u16* op = Vt + ((size_t)z * 128 + dy) * NN + sx;
#pragma unroll
  for (int i = 0; i < 32; i += 8)
    op[(size_t)(ty + i) * NN + tx] = t[tx][ty + i];
}

// ---------------- LayerNorm, wave per row, dual-pointer input; INBF: bf16 vs f32 input ---------
template <int INBF, int OUTBF>
__global__ __launch_bounds__(256) void ln_kernel(const void* __restrict__ x0,
                                                 const void* __restrict__ x1,
                                                 const float* __restrict__ g,
                                                 const float* __restrict__ bb,
                                                 void* __restrict__ out) {
  int l = threadIdx.x & 63, w = threadIdx.x >> 6;
  size_t row = (size_t)blockIdx.x * 4 + w;
  float xs[8];
  if (INBF) {
    const u16* xr = (row < RR) ? ((const u16*)x0 + row * DD)
                               : ((const u16*)x1 + (row - RR) * DD);
    u16x8 v = *(const u16x8*)(xr + l * 8);
#pragma unroll
    for (int j = 0; j < 8; j++) xs[j] = b2f(v[j]);
  } else {
    const float* xr = (row < RR) ? ((const float*)x0 + row * DD)
                                 : ((const float*)x1 + (row - RR) * DD);
    float4 v0 = *(const float4*)(xr + l * 8);
    float4 v1 = *(const float4*)(xr + l * 8 + 4);
    xs[0] = v0.x; xs[1] = v0.y; xs[2] = v0.z; xs[3] = v0.w;
    xs[4] = v1.x; xs[5] = v1.y; xs[6] = v1.z; xs[7] = v1.w;
  }
  float sum = 0.0f, sq = 0.0f;
#pragma unroll
  for (int j = 0; j < 8; j++) { sum += xs[j]; sq += xs[j] * xs[j]; }
#pragma unroll
  for (int o = 1; o < 64; o <<= 1) {
    sum += __shfl_xor(sum, o);
    sq += __shfl_xor(sq, o);
  }
  float mean = sum * (1.0f / DD);
  float var = fmaxf((sq - (float)DD * mean * mean) * (1.0f / (DD - 1)), 0.0f);
  float inv = 1.0f / (sqrtf(var) + 1e-6f);
  float4 g0 = *(const float4*)(g + l * 8), g1 = *(const float4*)(g + l * 8 + 4);
  float4 b0 = *(const float4*)(bb + l * 8), b1 = *(const float4*)(bb + l * 8 + 4);
  float gs[8] = {g0.x, g0.y, g0.z, g0.w, g1.x, g1.y, g1.z, g1.w};
  float bs[8] = {b0.x, b0.y, b0.z, b0.w, b1.x, b1.y, b1.z, b1.w};
  float y[8];
#pragma unroll
  for (int j = 0; j < 8; j++) y[j] = (xs[j] - mean) * inv * gs[j] + bs[j];
  if (OUTBF) {
    u16x8 o8;
#pragma unroll
    for (int j = 0; j < 8; j++) o8[j] = f32_to_bf16(y[j]);
    *(u16x8*)((u16*)out + row * DD + l * 8) = o8;
  } else {
    float4 o0 = {y[0], y[1], y[2], y[3]};
    float4 o1 = {y[4], y[5], y[6], y[7]};
    *(float4*)((float*)out + row * DD + l * 8) = o0;
    *(float4*)((float*)out + row * DD + l * 8 + 4) = o1;
  }
}

// ---------------- GEMM (round-7 proven core): 256x128, 8 waves, BK=64, 3-buf ring, vmcnt(6) ----
// RESMODE: 0=no residual, 1=f32 residual, 2=bf16 residual. Output always bf16.
template <bool RELU, int RESMODE>
__global__ __launch_bounds__(512, 2) void gemm_bt(const u16* __restrict__ A, int lda,
                                                  const u16* __restrict__ Bt,
                                                  const float* __restrict__ bias,
                                                  const void* res0, const void* res1,
                                                  void* Cout, int ldc,
                                                  int N2, int Kd, int gy) {
  __shared__ u16 sA[3][2048 * 8];  // 96KB
  __shared__ u16 sB[3][1024 * 8];  // 48KB
  int tid = threadIdx.x;
  int l = tid & 63, w = tid >> 6;
  int wm = (w >> 1) * 64, wn = (w & 1) * 64;
  int nwg = gridDim.x;
  int chunkn = nwg >> 3;
  int g = blockIdx.x;
  int wg = (g & 7) * chunkn + (g >> 3);
  int bx = wg / gy, by = wg - bx * gy;
  int m0 = bx * 256, n0 = by * 128;
  f32x4 acc[4][4] = {};

  auto stageA = [&](int buf, int k0) {
#pragma unroll
    for (int is = 0; is < 4; is++) {
      int slot = is * 512 + tid;
      int chunk = slot >> 8, row = slot & 255;
      gl16(&sA[buf][(size_t)(is * 512 + w * 64) * 8],
           A + (size_t)(m0 + row) * lda + k0 + chunk * 8);
    }
  };
  auto stageB = [&](int buf, int k0) {
#pragma unroll
    for (int is = 0; is < 2; is++) {
      int slot = is * 512 + tid;
      int chunk = slot >> 7, row = slot & 127;
      gl16(&sB[buf][(size_t)(is * 512 + w * 64) * 8],
           Bt + (size_t)(n0 + row) * Kd + k0 + chunk * 8);
    }
  };
  int NT = Kd >> 6;
  stageA(0, 0); stageB(0, 0);
  stageA(1, 64); stageB(1, 64);
  int bi = 0;
  for (int t = 0; t < NT; t++) {
    if (t + 1 < NT) asm volatile("s_waitcnt vmcnt(6)" ::: "memory");
    else            asm volatile("s_waitcnt vmcnt(0)" ::: "memory");
    __builtin_amdgcn_s_barrier();
    __builtin_amdgcn_sched_barrier(0);
    int b2 = bi + 2; if (b2 >= 3) b2 -= 3;
    int k2 = (t + 2) * 64;
    u16x8 bfr[4][2], afr[2][2];
#pragma unroll
    for (int j = 0; j < 4; j++)
#pragma unroll
      for (int ks = 0; ks < 2; ks++)
        bfr[j][ks] = *(const u16x8*)&sB[bi][((size_t)(ks * 4 + (l >> 4)) * 128 + wn + j * 16 + (l & 15)) * 8];
#pragma unroll
    for (int i = 0; i < 2; i++)
#pragma unroll
      for (int ks = 0; ks < 2; ks++)
        afr[i][ks] = *(const u16x8*)&sA[bi][((size_t)(ks * 4 + (l >> 4)) * 256 + wm + i * 16 + (l & 15)) * 8];
    if (t + 2 < NT) stageA(b2, k2);
    __builtin_amdgcn_s_setprio(1);
#pragma unroll
    for (int ks = 0; ks < 2; ks++)
#pragma unroll
      for (int i = 0; i < 2; i++)
#pragma unroll
        for (int j = 0; j < 4; j++)
          acc[i][j] = mfma16(afr[i][ks], bfr[j][ks], acc[i][j]);
    __builtin_amdgcn_s_setprio(0);
    __builtin_amdgcn_s_barrier();
    u16x8 afr2[2][2];
#pragma unroll
    for (int i = 0; i < 2; i++)
#pragma unroll
      for (int ks = 0; ks < 2; ks++)
        afr2[i][ks] = *(const u16x8*)&sA[bi][((size_t)(ks * 4 + (l >> 4)) * 256 + wm + (i + 2) * 16 + (l & 15)) * 8];
    if (t + 2 < NT) stageB(b2, k2);
    __builtin_amdgcn_s_setprio(1);
#pragma unroll
    for (int ks = 0; ks < 2; ks++)
#pragma unroll
      for (int i = 0; i < 2; i++)
#pragma unroll
        for (int j = 0; j < 4; j++)
          acc[i + 2][j] = mfma16(afr2[i][ks], bfr[j][ks], acc[i + 2][j]);
    __builtin_amdgcn_s_setprio(0);
    bi++; if (bi >= 3) bi = 0;
  }
  // ---- epilogue: LDS-transposed, vectorized ----
  __syncthreads();
  float* eTw = (float*)&sA[0][0] + w * 1024;
  float4 bias4 = *(const float4*)&bias[n0 + wn + (l & 15) * 4];
#pragma unroll
  for (int i = 0; i < 4; i++) {
#pragma unroll
    for (int j = 0; j < 4; j++)
#pragma unroll
      for (int r = 0; r < 4; r++)
        eTw[((l >> 4) * 4 + r) * 64 + j * 16 + (l & 15)] = acc[i][j][r];
#pragma unroll
    for (int t = 0; t < 4; t++) {
      int row = t * 4 + (l >> 4);
      int f4 = l & 15;
      float4 v4 = *(float4*)&eTw[row * 64 + f4 * 4];
      int gm = m0 + wm + i * 16 + row;
      int gn = n0 + wn + f4 * 4;
      v4.x += bias4.x; v4.y += bias4.y; v4.z += bias4.z; v4.w += bias4.w;
      if (RELU) {
        v4.x = fmaxf(v4.x, 0.0f); v4.y = fmaxf(v4.y, 0.0f);
        v4.z = fmaxf(v4.z, 0.0f); v4.w = fmaxf(v4.w, 0.0f);
      }
      if (RESMODE == 1) {
        const float* rp = (gm < RR) ? ((const float*)res0 + (size_t)gm * DD)
                                    : ((const float*)res1 + (size_t)(gm - RR) * DD);
        float4 r4 = *(const float4*)&rp[gn];
        v4.x += r4.x; v4.y += r4.y; v4.z += r4.z; v4.w += r4.w;
      } else if (RESMODE == 2) {
        const u16* rp = (gm < RR) ? ((const u16*)res0 + (size_t)gm * DD)
                                  : ((const u16*)res1 + (size_t)(gm - RR) * DD);
        u16x4 r4 = *(const u16x4*)&rp[gn];
        v4.x += b2f(r4[0]); v4.y += b2f(r4[1]); v4.z += b2f(r4[2]); v4.w += b2f(r4[3]);
      }
      u16x4 o4;
      o4[0] = f32_to_bf16(v4.x); o4[1] = f32_to_bf16(v4.y);
      o4[2] = f32_to_bf16(v4.z); o4[3] = f32_to_bf16(v4.w);
      *(u16x4*)&((u16*)Cout)[(size_t)gm * ldc + gn] = o4;
    }
  }
}

// ---------------- flash attention: 8 waves x 16 q-rows (QBLK=128), KVBLK=64, fixed-max ----------
__global__ __launch_bounds__(512, 4) void attn_kernel(const u16* __restrict__ Q, int qstride,
                                                      const u16* __restrict__ K, int kstride,
                                                      const u16* __restrict__ Vt,
                                                      u16* __restrict__ O, int ostride) {
  __shared__ u16 sK[2][64 * 128];
  __shared__ u16 sV[2][128 * 64];
  __shared__ u16 sP[8][16 * 64];
  int tid = threadIdx.x;
  int l = tid & 63, w = tid >> 6;
  int p = blockIdx.x;
  int xcd = p & 7, slot = p >> 3;
  int qb = slot & 7, ghigh = slot >> 3;
  int g = ghigh * 8 + xcd;
  int b = g >> 2, h = g & 3;
  int q0 = qb * 128 + w * 16;
  int bh = g;

  const u16* Qg = Q + (size_t)b * NN * qstride + h * 128;
  const u16* Kg = K + (size_t)b * NN * kstride + h * 128;
  const u16* Vg = Vt + (size_t)bh * 128 * NN;

  u16x8 qf[4];
#pragma unroll
  for (int c = 0; c < 4; c++)
    qf[c] = *(const u16x8*)(Qg + (size_t)(q0 + (l & 15)) * qstride + c * 32 + (l >> 4) * 8);

  f32x4 oacc[8] = {};
  float psum[4] = {0.0f, 0.0f, 0.0f, 0.0f};
  const float scale = 0.08838834764831843f;

  auto stage = [&](int buf, int k0) {
#pragma unroll
    for (int is = 0; is < 2; is++) {
      int slot2 = is * 512 + tid;
      {
        int row = slot2 >> 4, c16 = slot2 & 15;
        int colb = (c16 * 16) ^ ((row & 7) << 4);
        gl16(&sK[buf][(size_t)(is * 512 + w * 64) * 8],
             Kg + (size_t)(k0 + row) * kstride + (colb >> 1));
      }
      {
        int drow = slot2 >> 3, c16 = slot2 & 7;
        int colb = (c16 * 16) ^ ((drow & 7) << 4);
        gl16(&sV[buf][(size_t)(is * 512 + w * 64) * 8],
             Vg + (size_t)drow * NN + k0 + (colb >> 1));
      }
    }
  };

  stage(0, 0);
  int buf = 0;
  for (int t = 0; t < NN / 64; t++) {
    __syncthreads();
    if (t + 1 < NN / 64) stage(buf ^ 1, (t + 1) * 64);
    f32x4 sc[4] = {};
    __builtin_amdgcn_s_setprio(1);
#pragma unroll
    for (int ks = 0; ks < 4; ks++) {
      int row = ks * 16 + (l & 15);
      int swz = (row & 7) << 4;
#pragma unroll
      for (int c = 0; c < 4; c++) {
        int colb = (c * 64 + (l >> 4) * 16) ^ swz;
        u16x8 kf = *(const u16x8*)&sK[buf][row * 128 + (colb >> 1)];
        sc[ks] = mfma16(qf[c], kf, sc[ks]);
      }
    }
    __builtin_amdgcn_s_setprio(0);
#pragma unroll
    for (int r = 0; r < 4; r++) {
      int prow = (l >> 4) * 4 + r;
      int pswz = (prow & 7) << 4;
#pragma unroll
      for (int ks = 0; ks < 4; ks++) {
        float pp = __expf(sc[ks][r] * scale);
        psum[r] += pp;
        int colb = ((ks * 16 + (l & 15)) * 2) ^ pswz;
        sP[w][prow * 64 + (colb >> 1)] = f32_to_bf16(pp);
      }
    }
    u16x8 pf[2];
#pragma unroll
    for (int kc = 0; kc < 2; kc++) {
      int prow = l & 15;
      int colb = (kc * 64 + (l >> 4) * 16) ^ ((prow & 7) << 4);
      pf[kc] = *(const u16x8*)&sP[w][prow * 64 + (colb >> 1)];
    }
    __builtin_amdgcn_s_setprio(1);
#pragma unroll
    for (int n = 0; n < 8; n++) {
      int drow = n * 16 + (l & 15);
      int swz = (drow & 7) << 4;
#pragma unroll
      for (int kc = 0; kc < 2; kc++) {
        int colb = (kc * 64 + (l >> 4) * 16) ^ swz;
        u16x8 vf = *(const u16x8*)&sV[buf][drow * 64 + (colb >> 1)];
        oacc[n] = mfma16(pf[kc], vf, oacc[n]);
      }
    }
    __builtin_amdgcn_s_setprio(0);
    buf ^= 1;
  }
#pragma unroll
  for (int r = 0; r < 4; r++) {
    psum[r] += __shfl_xor(psum[r], 1);
    psum[r] += __shfl_xor(psum[r], 2);
    psum[r] += __shfl_xor(psum[r], 4);
    psum[r] += __shfl_xor(psum[r], 8);
  }
#pragma unroll
  for (int r = 0; r < 4; r++) {
    float inv = 1.0f / psum[r];
    int grow = q0 + (l >> 4) * 4 + r;
    u16* Op = O + ((size_t)b * NN + grow) * ostride + h * 128 + (l & 15);
#pragma unroll
    for (int n = 0; n < 8; n++) Op[n * 16] = f32_to_bf16(oacc[n][r] * inv);
  }
}

// ---------------- host orchestration ----------------
extern "C" void kernel_launch(void* const* d_in, const int* in_sizes, int n_in,
                              void* d_out, int out_size, void* d_ws, size_t ws_size,
                              hipStream_t stream) {
  const float* src = (const float*)d_in[0];
  const float* tgt = (const float*)d_in[1];
  const float* enc_attn_w = (const float*)d_in[2];
  const float* enc_attn_b = (const float*)d_in[3];
  const float* enc_ff_w1 = (const float*)d_in[4];
  const float* enc_ff_b1 = (const float*)d_in[5];
  const float* enc_ff_w2 = (const float*)d_in[6];
  const float* enc_ff_b2 = (const float*)d_in[7];
  const float* enc_ln_g = (const float*)d_in[8];
  const float* enc_ln_b = (const float*)d_in[9];
  const float* dec_sa_w = (const float*)d_in[10];
  const float* dec_sa_b = (const float*)d_in[11];
  const float* dec_ca_w = (const float*)d_in[12];
  const float* dec_ca_b = (const float*)d_in[13];
  const float* dec_ff_w1 = (const float*)d_in[14];
  const float* dec_ff_b1 = (const float*)d_in[15];
  const float* dec_ff_w2 = (const float*)d_in[16];
  const float* dec_ff_b2 = (const float*)d_in[17];
  const float* dec_ln_g = (const float*)d_in[18];
  const float* dec_ln_b = (const float*)d_in[19];

  // ---- workspace layout ----
  u16* wp = (u16*)d_ws;
  u16* wE = wp;   wp += 4 * DD * DD;
  u16* wS = wp;   wp += 4 * DD * DD;
  u16* wC = wp;   wp += 4 * DD * DD;
  u16* wEff1 = wp; wp += DD * DFFK;
  u16* wEff2 = wp; wp += DD * DFFK;
  u16* wDff1 = wp; wp += DD * DFFK;
  u16* wDff2 = wp; wp += DD * DFFK;
  char* p = (char*)wp;
  float* sT = (float*)p;  p += (size_t)RR * DD * 4;
  float* tT = (float*)p;  p += (size_t)RR * DD * 4;
  u16* xb = (u16*)p;      p += (size_t)MM * DD * 2;   // bf16 residual trunk
  u16* hb = (u16*)p;      p += (size_t)MM * DD * 2;
  u16* memb = (u16*)p;    p += (size_t)MM * DD * 2;
  u16* Vt = (u16*)p;      p += (size_t)16 * HH * 128 * NN * 2;
  u16* U = (u16*)p;       p += (size_t)MM * 3 * DD * 2;   // QKV / ffh / xtmp union
  u16* xb1 = xb + (size_t)RR * DD;
  float* xtmp = (float*)U;

  // ---- weight conversion ----
  wconv_kernel<<<(4 * DD * DD + 255) / 256, 256, 0, stream>>>(enc_attn_w, wE, DD, DD, 4);
  wconv_kernel<<<(4 * DD * DD + 255) / 256, 256, 0, stream>>>(dec_sa_w, wS, DD, DD, 4);
  wconv_kernel<<<(4 * DD * DD + 255) / 256, 256, 0, stream>>>(dec_ca_w, wC, DD, DD, 4);
  wconv_kernel<<<(DD * DFFK + 255) / 256, 256, 0, stream>>>(enc_ff_w1, wEff1, DD, DFFK, 1);
  wconv_kernel<<<(DD * DFFK + 255) / 256, 256, 0, stream>>>(enc_ff_w2, wEff2, DFFK, DD, 1);
  wconv_kernel<<<(DD * DFFK + 255) / 256, 256, 0, stream>>>(dec_ff_w1, wDff1, DD, DFFK, 1);
  wconv_kernel<<<(DD * DFFK + 255) / 256, 256, 0, stream>>>(dec_ff_w2, wDff2, DFFK, DD, 1);

  // ---- input transposes: [B][D][N] -> [B][N][D] ----
  transpose_kernel<<<dim3(NN / 32, DD / 32, BB), dim3(32, 8), 0, stream>>>(src, sT, DD, NN);
  transpose_kernel<<<dim3(NN / 32, DD / 32, BB), dim3(32, 8), 0, stream>>>(tgt, tT, DD, NN);

  // ln variants: inbf/outbf
  auto lnf = [&](const float* x0, const float* x1, const float* g, const float* b, u16* out) {
    ln_kernel<0, 1><<<MM / 4, 256, 0, stream>>>(x0, x1, g, b, out);
  };
  auto lnb = [&](const u16* x0, const u16* x1, const float* g, const float* b, u16* out) {
    ln_kernel<1, 1><<<MM / 4, 256, 0, stream>>>(x0, x1, g, b, out);
  };
  auto lnbf32 = [&](const u16* x0, const u16* x1, const float* g, const float* b, float* out) {
    ln_kernel<1, 0><<<MM / 4, 256, 0, stream>>>(x0, x1, g, b, out);
  };
  // gemm modes: 0=plain, 1=relu, 2=res-f32, 3=res-bf16
  auto gemm = [&](const u16* A, int lda, const u16* W, const float* bias,
                  const void* r0, const void* r1, void* out, int ldc,
                  int N2, int K, int mode) {
    int gy = N2 / 128;
    dim3 g((MM / 256) * gy);
    if (mode == 0)
      gemm_bt<false, 0><<<g, 512, 0, stream>>>(A, lda, W, bias, nullptr, nullptr, out, ldc, N2, K, gy);
    else if (mode == 1)
      gemm_bt<true, 0><<<g, 512, 0, stream>>>(A, lda, W, bias, nullptr, nullptr, out, ldc, N2, K, gy);
    else if (mode == 2)
      gemm_bt<false, 1><<<g, 512, 0, stream>>>(A, lda, W, bias, r0, r1, out, ldc, N2, K, gy);
    else
      gemm_bt<false, 2><<<g, 512, 0, stream>>>(A, lda, W, bias, r0, r1, out, ldc, N2, K, gy);
  };
  auto vtrans = [&]() {
    vtrans_kernel<<<dim3(NN / 32, 4, 64), dim3(32, 8), 0, stream>>>(U + 2 * DD, 3 * DD, Vt);
  };
  auto attn = [&]() {
    attn_kernel<<<dim3(512), 512, 0, stream>>>(U, 3 * DD, U + DD, 3 * DD, Vt,
                                               U + 2 * DD, 3 * DD);
  };
  u16* ab = U + 2 * DD;

  // ================= batched pass: rows [0,RR)=model A (enc sT, dec tT), [RR,MM)=model B ======
  // ---- encoder ----
  lnf(sT, tT, enc_ln_g, enc_ln_b, hb);
  gemm(hb, DD, wE, enc_attn_b, nullptr, nullptr, U, 3 * DD, 3 * DD, DD, 0);
  vtrans();
  attn();
  gemm(ab, 3 * DD, wE + 3 * DD * DD, enc_attn_b + 3 * DD, sT, tT, xb, DD, DD, DD, 2);
  lnb(xb, xb1, enc_ln_g + DD, enc_ln_b + DD, hb);
  gemm(hb, DD, wEff1, enc_ff_b1, nullptr, nullptr, U, DFFK, DFFK, DD, 1);
  gemm(U, DFFK, wEff2, enc_ff_b2, xb, xb1, xb, DD, DD, DFFK, 3);
  lnb(xb, xb1, enc_ln_g + 2 * DD, enc_ln_b + 2 * DD, memb);
  // ---- decoder self-attn ----
  lnf(tT, sT, dec_ln_g, dec_ln_b, hb);
  gemm(hb, DD, wS, dec_sa_b, nullptr, nullptr, U, 3 * DD, 3 * DD, DD, 0);
  vtrans();
  attn();
  gemm(ab, 3 * DD, wS + 3 * DD * DD, dec_sa_b + 3 * DD, tT, sT, xb, DD, DD, DD, 2);
  // ---- decoder cross-attn ----
  lnb(xb, xb1, dec_ln_g + DD, dec_ln_b + DD, hb);
  gemm(hb, DD, wC, dec_ca_b, nullptr, nullptr, U, 3 * DD, DD, DD, 0);
  gemm(memb, DD, wC + DD * DD, dec_ca_b + DD, nullptr, nullptr, U + DD, 3 * DD,
       2 * DD, DD, 0);
  vtrans();
  attn();
  gemm(ab, 3 * DD, wC + 3 * DD * DD, dec_ca_b + 3 * DD, xb, xb1, xb, DD, DD, DD, 3);
  // ---- decoder FFN ----
  lnb(xb, xb1, dec_ln_g + 2 * DD, dec_ln_b + 2 * DD, hb);
  gemm(hb, DD, wDff1, dec_ff_b1, nullptr, nullptr, U, DFFK, DFFK, DD, 1);
  gemm(U, DFFK, wDff2, dec_ff_b2, xb, xb1, xb, DD, DD, DFFK, 3);
  lnbf32(xb, xb1, dec_ln_g + 3 * DD, dec_ln_b + 3 * DD, xtmp);
  // ---- output transpose ----
  float* out_f = (float*)d_out;
  out_trans_kernel<<<dim3(DD / 32, NN / 32, 16), dim3(32, 8), 0, stream>>>(
      xtmp, out_f + (size_t)RR * DD, out_f);
}

// Round 16
// 649.640 us; speedup vs baseline: 1.0579x; 1.0036x over previous
//
#include <hip/hip_runtime.h>

#define BB 8
#define NN 1024
#define DD 512
#define DFFK 1024
#define HH 4
#define RR (BB * NN)     // 8192 rows per model
#define MM (2 * RR)      // 16384 combined rows

typedef unsigned short u16;
typedef u16 u16x8 __attribute__((ext_vector_type(8)));
typedef u16 u16x4 __attribute__((ext_vector_type(4)));
typedef float f32x4 __attribute__((ext_vector_type(4)));
typedef __bf16 bf16x8 __attribute__((ext_vector_type(8)));

__device__ __forceinline__ u16 f32_to_bf16(float f) {
  unsigned int u = __builtin_bit_cast(unsigned int, f);
  unsigned int r = u + 0x7FFFu + ((u >> 16) & 1u);
  return (u16)(r >> 16);
}

__device__ __forceinline__ float b2f(u16 u) {
  unsigned int v = ((unsigned int)u) << 16;
  return __builtin_bit_cast(float, v);
}

__device__ __forceinline__ f32x4 mfma16(u16x8 a, u16x8 b, f32x4 c) {
  return __builtin_amdgcn_mfma_f32_16x16x32_bf16(
      __builtin_bit_cast(bf16x8, a), __builtin_bit_cast(bf16x8, b), c, 0, 0, 0);
}

__device__ __forceinline__ void gl16(u16* lds, const u16* g) {
  __builtin_amdgcn_global_load_lds(
      (const __attribute__((address_space(1))) unsigned int*)g,
      (__attribute__((address_space(3))) unsigned int*)lds, 16, 0, 0);
}

// ---------------- weight convert: nmat matrices W[K][N2] f32 -> Wt[N2][K] bf16 ----------------
__global__ __launch_bounds__(256) void wconv_kernel(const float* __restrict__ W,
                                                    u16* __restrict__ Wt, int K, int N2, int nmat) {
  int idx = blockIdx.x * 256 + threadIdx.x;
  if (idx >= nmat * K * N2) return;
  int mat = idx / (K * N2), rem = idx % (K * N2);
  int k = rem % K, n = rem / K;
  Wt[(size_t)mat * K * N2 + (size_t)n * K + k] =
      f32_to_bf16(W[(size_t)mat * K * N2 + (size_t)k * N2 + n]);
}

// ---------------- input transpose: per batch z, in[R_][C_] -> out[C_][R_] ----------------
__global__ __launch_bounds__(256) void transpose_kernel(const float* __restrict__ in,
                                                        float* __restrict__ out, int R_, int C_) {
  __shared__ float t[32][33];
  int bx = blockIdx.x * 32, by = blockIdx.y * 32;
  size_t zoff = (size_t)blockIdx.z * R_ * C_;
  const float* ip = in + zoff;
  float* op = out + zoff;
  int tx = threadIdx.x, ty = threadIdx.y;
#pragma unroll
  for (int i = 0; i < 32; i += 8)
    t[ty + i][tx] = ip[(size_t)(by + ty + i) * C_ + bx + tx];
  __syncthreads();
#pragma unroll
  for (int i = 0; i < 32; i += 8)
    op[(size_t)(bx + ty + i) * R_ + by + tx] = t[tx][ty + i];
}

// ---------------- output transpose: xtmp[MM][DD] -> per z (16): dst[DD][NN] ----------------
__global__ __launch_bounds__(256) void out_trans_kernel(const float* __restrict__ in,
                                                        float* __restrict__ outA,
                                                        float* __restrict__ outB) {
  __shared__ float t[32][33];
  int z = blockIdx.z;
  int dx = blockIdx.x * 32;
  int sy = blockIdx.y * 32;
  int tx = threadIdx.x, ty = threadIdx.y;
  const float* ip = in + (size_t)z * NN * DD;
#pragma unroll
  for (int i = 0; i < 32; i += 8)
    t[ty + i][tx] = ip[(size_t)(sy + ty + i) * DD + dx + tx];
  __syncthreads();
  float* dst = (z < BB) ? (outA + (size_t)z * DD * NN) : (outB + (size_t)(z - BB) * DD * NN);
#pragma unroll
  for (int i = 0; i < 32; i += 8)
    dst[(size_t)(dx + ty + i) * NN + sy + tx] = t[tx][ty + i];
}

// ---------------- bf16 V transpose: V[t][*vstride] -> Vt[bh][d][seq] ----------------
__global__ __launch_bounds__(256) void vtrans_kernel(const u16* __restrict__ V, int vstride,
                                                     u16* __restrict__ Vt) {
  __shared__ u16 t[32][33];
  int z = blockIdx.z;
  int b = z >> 2, h = z & 3;
  int sx = blockIdx.x * 32;
  int dy = blockIdx.y * 32;
  int tx = threadIdx.x, ty = threadIdx.y;
  const u16* ip = V + (size_t)b * NN * vstride + h * 128 + dy;
#pragma unroll
  for (int i = 0; i < 32; i += 8)
    t[ty + i][tx] = ip[(size_t)(sx + ty + i) * vstride + tx];
  __syncthreads();
  u16* op = Vt + ((size_t)z * 128 + dy) * NN + sx;
#pragma unroll
  for (int i = 0; i < 32; i += 8)
    op[(size_t)(ty + i) * NN + tx] = t[tx][ty + i];
}

// ---------------- LayerNorm, wave per row, dual-pointer input; INBF: bf16 vs f32 input ---------
template <int INBF, int OUTBF>
__global__ __launch_bounds__(256) void ln_kernel(const void* __restrict__ x0,
                                                 const void* __restrict__ x1,
                                                 const float* __restrict__ g,
                                                 const float* __restrict__ bb,
                                                 void* __restrict__ out) {
  int l = threadIdx.x & 63, w = threadIdx.x >> 6;
  size_t row = (size_t)blockIdx.x * 4 + w;
  float xs[8];
  if (INBF) {
    const u16* xr = (row < RR) ? ((const u16*)x0 + row * DD)
                               : ((const u16*)x1 + (row - RR) * DD);
    u16x8 v = *(const u16x8*)(xr + l * 8);
#pragma unroll
    for (int j = 0; j < 8; j++) xs[j] = b2f(v[j]);
  } else {
    const float* xr = (row < RR) ? ((const float*)x0 + row * DD)
                                 : ((const float*)x1 + (row - RR) * DD);
    float4 v0 = *(const float4*)(xr + l * 8);
    float4 v1 = *(const float4*)(xr + l * 8 + 4);
    xs[0] = v0.x; xs[1] = v0.y; xs[2] = v0.z; xs[3] = v0.w;
    xs[4] = v1.x; xs[5] = v1.y; xs[6] = v1.z; xs[7] = v1.w;
  }
  float sum = 0.0f, sq = 0.0f;
#pragma unroll
  for (int j = 0; j < 8; j++) { sum += xs[j]; sq += xs[j] * xs[j]; }
#pragma unroll
  for (int o = 1; o < 64; o <<= 1) {
    sum += __shfl_xor(sum, o);
    sq += __shfl_xor(sq, o);
  }
  float mean = sum * (1.0f / DD);
  float var = fmaxf((sq - (float)DD * mean * mean) * (1.0f / (DD - 1)), 0.0f);
  float inv = 1.0f / (sqrtf(var) + 1e-6f);
  float4 g0 = *(const float4*)(g + l * 8), g1 = *(const float4*)(g + l * 8 + 4);
  float4 b0 = *(const float4*)(bb + l * 8), b1 = *(const float4*)(bb + l * 8 + 4);
  float gs[8] = {g0.x, g0.y, g0.z, g0.w, g1.x, g1.y, g1.z, g1.w};
  float bs[8] = {b0.x, b0.y, b0.z, b0.w, b1.x, b1.y, b1.z, b1.w};
  float y[8];
#pragma unroll
  for (int j = 0; j < 8; j++) y[j] = (xs[j] - mean) * inv * gs[j] + bs[j];
  if (OUTBF) {
    u16x8 o8;
#pragma unroll
    for (int j = 0; j < 8; j++) o8[j] = f32_to_bf16(y[j]);
    *(u16x8*)((u16*)out + row * DD + l * 8) = o8;
  } else {
    float4 o0 = {y[0], y[1], y[2], y[3]};
    float4 o1 = {y[4], y[5], y[6], y[7]};
    *(float4*)((float*)out + row * DD + l * 8) = o0;
    *(float4*)((float*)out + row * DD + l * 8 + 4) = o1;
  }
}

// ---------------- GEMM (round-7 proven core): 256x128, 8 waves, BK=64, 3-buf ring, vmcnt(6) ----
// RESMODE: 0=no residual, 1=f32 residual, 2=bf16 residual. Output always bf16.
template <bool RELU, int RESMODE>
__global__ __launch_bounds__(512, 2) void gemm_bt(const u16* __restrict__ A, int lda,
                                                  const u16* __restrict__ Bt,
                                                  const float* __restrict__ bias,
                                                  const void* res0, const void* res1,
                                                  void* Cout, int ldc,
                                                  int N2, int Kd, int gy) {
  __shared__ u16 sA[3][2048 * 8];  // 96KB
  __shared__ u16 sB[3][1024 * 8];  // 48KB
  int tid = threadIdx.x;
  int l = tid & 63, w = tid >> 6;
  int wm = (w >> 1) * 64, wn = (w & 1) * 64;
  int nwg = gridDim.x;
  int chunkn = nwg >> 3;
  int g = blockIdx.x;
  int wg = (g & 7) * chunkn + (g >> 3);
  int bx = wg / gy, by = wg - bx * gy;
  int m0 = bx * 256, n0 = by * 128;
  f32x4 acc[4][4] = {};

  auto stageA = [&](int buf, int k0) {
#pragma unroll
    for (int is = 0; is < 4; is++) {
      int slot = is * 512 + tid;
      int chunk = slot >> 8, row = slot & 255;
      gl16(&sA[buf][(size_t)(is * 512 + w * 64) * 8],
           A + (size_t)(m0 + row) * lda + k0 + chunk * 8);
    }
  };
  auto stageB = [&](int buf, int k0) {
#pragma unroll
    for (int is = 0; is < 2; is++) {
      int slot = is * 512 + tid;
      int chunk = slot >> 7, row = slot & 127;
      gl16(&sB[buf][(size_t)(is * 512 + w * 64) * 8],
           Bt + (size_t)(n0 + row) * Kd + k0 + chunk * 8);
    }
  };
  int NT = Kd >> 6;
  stageA(0, 0); stageB(0, 0);
  stageA(1, 64); stageB(1, 64);
  int bi = 0;
  for (int t = 0; t < NT; t++) {
    if (t + 1 < NT) asm volatile("s_waitcnt vmcnt(6)" ::: "memory");
    else            asm volatile("s_waitcnt vmcnt(0)" ::: "memory");
    __builtin_amdgcn_s_barrier();
    __builtin_amdgcn_sched_barrier(0);
    int b2 = bi + 2; if (b2 >= 3) b2 -= 3;
    int k2 = (t + 2) * 64;
    u16x8 bfr[4][2], afr[2][2];
#pragma unroll
    for (int j = 0; j < 4; j++)
#pragma unroll
      for (int ks = 0; ks < 2; ks++)
        bfr[j][ks] = *(const u16x8*)&sB[bi][((size_t)(ks * 4 + (l >> 4)) * 128 + wn + j * 16 + (l & 15)) * 8];
#pragma unroll
    for (int i = 0; i < 2; i++)
#pragma unroll
      for (int ks = 0; ks < 2; ks++)
        afr[i][ks] = *(const u16x8*)&sA[bi][((size_t)(ks * 4 + (l >> 4)) * 256 + wm + i * 16 + (l & 15)) * 8];
    if (t + 2 < NT) stageA(b2, k2);
    __builtin_amdgcn_s_setprio(1);
#pragma unroll
    for (int ks = 0; ks < 2; ks++)
#pragma unroll
      for (int i = 0; i < 2; i++)
#pragma unroll
        for (int j = 0; j < 4; j++)
          acc[i][j] = mfma16(afr[i][ks], bfr[j][ks], acc[i][j]);
    __builtin_amdgcn_s_setprio(0);
    __builtin_amdgcn_s_barrier();
    u16x8 afr2[2][2];
#pragma unroll
    for (int i = 0; i < 2; i++)
#pragma unroll
      for (int ks = 0; ks < 2; ks++)
        afr2[i][ks] = *(const u16x8*)&sA[bi][((size_t)(ks * 4 + (l >> 4)) * 256 + wm + (i + 2) * 16 + (l & 15)) * 8];
    if (t + 2 < NT) stageB(b2, k2);
    __builtin_amdgcn_s_setprio(1);
#pragma unroll
    for (int ks = 0; ks < 2; ks++)
#pragma unroll
      for (int i = 0; i < 2; i++)
#pragma unroll
        for (int j = 0; j < 4; j++)
          acc[i + 2][j] = mfma16(afr2[i][ks], bfr[j][ks], acc[i + 2][j]);
    __builtin_amdgcn_s_setprio(0);
    bi++; if (bi >= 3) bi = 0;
  }
  // ---- epilogue: LDS-transposed, vectorized ----
  __syncthreads();
  float* eTw = (float*)&sA[0][0] + w * 1024;
  float4 bias4 = *(const float4*)&bias[n0 + wn + (l & 15) * 4];
#pragma unroll
  for (int i = 0; i < 4; i++) {
#pragma unroll
    for (int j = 0; j < 4; j++)
#pragma unroll
      for (int r = 0; r < 4; r++)
        eTw[((l >> 4) * 4 + r) * 64 + j * 16 + (l & 15)] = acc[i][j][r];
#pragma unroll
    for (int t = 0; t < 4; t++) {
      int row = t * 4 + (l >> 4);
      int f4 = l & 15;
      float4 v4 = *(float4*)&eTw[row * 64 + f4 * 4];
      int gm = m0 + wm + i * 16 + row;
      int gn = n0 + wn + f4 * 4;
      v4.x += bias4.x; v4.y += bias4.y; v4.z += bias4.z; v4.w += bias4.w;
      if (RELU) {
        v4.x = fmaxf(v4.x, 0.0f); v4.y = fmaxf(v4.y, 0.0f);
        v4.z = fmaxf(v4.z, 0.0f); v4.w = fmaxf(v4.w, 0.0f);
      }
      if (RESMODE == 1) {
        const float* rp = (gm < RR) ? ((const float*)res0 + (size_t)gm * DD)
                                    : ((const float*)res1 + (size_t)(gm - RR) * DD);
        float4 r4 = *(const float4*)&rp[gn];
        v4.x += r4.x; v4.y += r4.y; v4.z += r4.z; v4.w += r4.w;
      } else if (RESMODE == 2) {
        const u16* rp = (gm < RR) ? ((const u16*)res0 + (size_t)gm * DD)
                                  : ((const u16*)res1 + (size_t)(gm - RR) * DD);
        u16x4 r4 = *(const u16x4*)&rp[gn];
        v4.x += b2f(r4[0]); v4.y += b2f(r4[1]); v4.z += b2f(r4[2]); v4.w += b2f(r4[3]);
      }
      u16x4 o4;
      o4[0] = f32_to_bf16(v4.x); o4[1] = f32_to_bf16(v4.y);
      o4[2] = f32_to_bf16(v4.z); o4[3] = f32_to_bf16(v4.w);
      *(u16x4*)&((u16*)Cout)[(size_t)gm * ldc + gn] = o4;
    }
  }
}

// ---------------- flash attention: 8 waves x 16 q-rows (QBLK=128), KVBLK=64, fixed-max ----------
__global__ __launch_bounds__(512, 4) void attn_kernel(const u16* __restrict__ Q, int qstride,
                                                      const u16* __restrict__ K, int kstride,
                                                      const u16* __restrict__ Vt,
                                                      u16* __restrict__ O, int ostride) {
  __shared__ u16 sK[2][64 * 128];
  __shared__ u16 sV[2][128 * 64];
  __shared__ u16 sP[8][16 * 64];
  int tid = threadIdx.x;
  int l = tid & 63, w = tid >> 6;
  int p = blockIdx.x;
  int xcd = p & 7, slot = p >> 3;
  int qb = slot & 7, ghigh = slot >> 3;
  int g = ghigh * 8 + xcd;
  int b = g >> 2, h = g & 3;
  int q0 = qb * 128 + w * 16;
  int bh = g;

  const u16* Qg = Q + (size_t)b * NN * qstride + h * 128;
  const u16* Kg = K + (size_t)b * NN * kstride + h * 128;
  const u16* Vg = Vt + (size_t)bh * 128 * NN;

  u16x8 qf[4];
#pragma unroll
  for (int c = 0; c < 4; c++)
    qf[c] = *(const u16x8*)(Qg + (size_t)(q0 + (l & 15)) * qstride + c * 32 + (l >> 4) * 8);

  f32x4 oacc[8] = {};
  float psum[4] = {0.0f, 0.0f, 0.0f, 0.0f};
  const float scale = 0.08838834764831843f;

  auto stage = [&](int buf, int k0) {
#pragma unroll
    for (int is = 0; is < 2; is++) {
      int slot2 = is * 512 + tid;
      {
        int row = slot2 >> 4, c16 = slot2 & 15;
        int colb = (c16 * 16) ^ ((row & 7) << 4);
        gl16(&sK[buf][(size_t)(is * 512 + w * 64) * 8],
             Kg + (size_t)(k0 + row) * kstride + (colb >> 1));
      }
      {
        int drow = slot2 >> 3, c16 = slot2 & 7;
        int colb = (c16 * 16) ^ ((drow & 7) << 4);
        gl16(&sV[buf][(size_t)(is * 512 + w * 64) * 8],
             Vg + (size_t)drow * NN + k0 + (colb >> 1));
      }
    }
  };

  stage(0, 0);
  int buf = 0;
  for (int t = 0; t < NN / 64; t++) {
    __syncthreads();
    if (t + 1 < NN / 64) stage(buf ^ 1, (t + 1) * 64);
    f32x4 sc[4] = {};
    __builtin_amdgcn_s_setprio(1);
#pragma unroll
    for (int ks = 0; ks < 4; ks++) {
      int row = ks * 16 + (l & 15);
      int swz = (row & 7) << 4;
#pragma unroll
      for (int c = 0; c < 4; c++) {
        int colb = (c * 64 + (l >> 4) * 16) ^ swz;
        u16x8 kf = *(const u16x8*)&sK[buf][row * 128 + (colb >> 1)];
        sc[ks] = mfma16(qf[c], kf, sc[ks]);
      }
    }
    __builtin_amdgcn_s_setprio(0);
#pragma unroll
    for (int r = 0; r < 4; r++) {
      int prow = (l >> 4) * 4 + r;
      int pswz = (prow & 7) << 4;
#pragma unroll
      for (int ks = 0; ks < 4; ks++) {
        float pp = __expf(sc[ks][r] * scale);
        psum[r] += pp;
        int colb = ((ks * 16 + (l & 15)) * 2) ^ pswz;
        sP[w][prow * 64 + (colb >> 1)] = f32_to_bf16(pp);
      }
    }
    u16x8 pf[2];
#pragma unroll
    for (int kc = 0; kc < 2; kc++) {
      int prow = l & 15;
      int colb = (kc * 64 + (l >> 4) * 16) ^ ((prow & 7) << 4);
      pf[kc] = *(const u16x8*)&sP[w][prow * 64 + (colb >> 1)];
    }
    __builtin_amdgcn_s_setprio(1);
#pragma unroll
    for (int n = 0; n < 8; n++) {
      int drow = n * 16 + (l & 15);
      int swz = (drow & 7) << 4;
#pragma unroll
      for (int kc = 0; kc < 2; kc++) {
        int colb = (kc * 64 + (l >> 4) * 16) ^ swz;
        u16x8 vf = *(const u16x8*)&sV[buf][drow * 64 + (colb >> 1)];
        oacc[n] = mfma16(pf[kc], vf, oacc[n]);
      }
    }
    __builtin_amdgcn_s_setprio(0);
    buf ^= 1;
  }
#pragma unroll
  for (int r = 0; r < 4; r++) {
    psum[r] += __shfl_xor(psum[r], 1);
    psum[r] += __shfl_xor(psum[r], 2);
    psum[r] += __shfl_xor(psum[r], 4);
    psum[r] += __shfl_xor(psum[r], 8);
  }
#pragma unroll
  for (int r = 0; r < 4; r++) {
    float inv = 1.0f / psum[r];
    int grow = q0 + (l >> 4) * 4 + r;
    u16* Op = O + ((size_t)b * NN + grow) * ostride + h * 128 + (l & 15);
#pragma unroll
    for (int n = 0; n < 8; n++) Op[n * 16] = f32_to_bf16(oacc[n][r] * inv);
  }
}

// ---------------- host orchestration ----------------
extern "C" void kernel_launch(void* const* d_in, const int* in_sizes, int n_in,
                              void* d_out, int out_size, void* d_ws, size_t ws_size,
                              hipStream_t stream) {
  const float* src = (const float*)d_in[0];
  const float* tgt = (const float*)d_in[1];
  const float* enc_attn_w = (const float*)d_in[2];
  const float* enc_attn_b = (const float*)d_in[3];
  const float* enc_ff_w1 = (const float*)d_in[4];
  const float* enc_ff_b1 = (const float*)d_in[5];
  const float* enc_ff_w2 = (const float*)d_in[6];
  const float* enc_ff_b2 = (const float*)d_in[7];
  const float* enc_ln_g = (const float*)d_in[8];
  const float* enc_ln_b = (const float*)d_in[9];
  const float* dec_sa_w = (const float*)d_in[10];
  const float* dec_sa_b = (const float*)d_in[11];
  const float* dec_ca_w = (const float*)d_in[12];
  const float* dec_ca_b = (const float*)d_in[13];
  const float* dec_ff_w1 = (const float*)d_in[14];
  const float* dec_ff_b1 = (const float*)d_in[15];
  const float* dec_ff_w2 = (const float*)d_in[16];
  const float* dec_ff_b2 = (const float*)d_in[17];
  const float* dec_ln_g = (const float*)d_in[18];
  const float* dec_ln_b = (const float*)d_in[19];

  // ---- workspace layout ----
  u16* wp = (u16*)d_ws;
  u16* wE = wp;   wp += 4 * DD * DD;
  u16* wS = wp;   wp += 4 * DD * DD;
  u16* wC = wp;   wp += 4 * DD * DD;
  u16* wEff1 = wp; wp += DD * DFFK;
  u16* wEff2 = wp; wp += DD * DFFK;
  u16* wDff1 = wp; wp += DD * DFFK;
  u16* wDff2 = wp; wp += DD * DFFK;
  char* p = (char*)wp;
  float* sT = (float*)p;  p += (size_t)RR * DD * 4;
  float* tT = (float*)p;  p += (size_t)RR * DD * 4;
  u16* xb = (u16*)p;      p += (size_t)MM * DD * 2;   // bf16 residual trunk
  u16* hb = (u16*)p;      p += (size_t)MM * DD * 2;
  u16* memb = (u16*)p;    p += (size_t)MM * DD * 2;
  u16* Vt = (u16*)p;      p += (size_t)16 * HH * 128 * NN * 2;
  u16* U = (u16*)p;       p += (size_t)MM * 3 * DD * 2;   // QKV / ffh / xtmp union
  u16* xb1 = xb + (size_t)RR * DD;
  float* xtmp = (float*)U;

  // ---- weight conversion ----
  wconv_kernel<<<(4 * DD * DD + 255) / 256, 256, 0, stream>>>(enc_attn_w, wE, DD, DD, 4);
  wconv_kernel<<<(4 * DD * DD + 255) / 256, 256, 0, stream>>>(dec_sa_w, wS, DD, DD, 4);
  wconv_kernel<<<(4 * DD * DD + 255) / 256, 256, 0, stream>>>(dec_ca_w, wC, DD, DD, 4);
  wconv_kernel<<<(DD * DFFK + 255) / 256, 256, 0, stream>>>(enc_ff_w1, wEff1, DD, DFFK, 1);
  wconv_kernel<<<(DD * DFFK + 255) / 256, 256, 0, stream>>>(enc_ff_w2, wEff2, DFFK, DD, 1);
  wconv_kernel<<<(DD * DFFK + 255) / 256, 256, 0, stream>>>(dec_ff_w1, wDff1, DD, DFFK, 1);
  wconv_kernel<<<(DD * DFFK + 255) / 256, 256, 0, stream>>>(dec_ff_w2, wDff2, DFFK, DD, 1);

  // ---- input transposes: [B][D][N] -> [B][N][D] ----
  transpose_kernel<<<dim3(NN / 32, DD / 32, BB), dim3(32, 8), 0, stream>>>(src, sT, DD, NN);
  transpose_kernel<<<dim3(NN / 32, DD / 32, BB), dim3(32, 8), 0, stream>>>(tgt, tT, DD, NN);

  auto lnf = [&](const float* x0, const float* x1, const float* g, const float* b, u16* out) {
    ln_kernel<0, 1><<<MM / 4, 256, 0, stream>>>(x0, x1, g, b, out);
  };
  auto lnb = [&](const u16* x0, const u16* x1, const float* g, const float* b, u16* out) {
    ln_kernel<1, 1><<<MM / 4, 256, 0, stream>>>(x0, x1, g, b, out);
  };
  auto lnbf32 = [&](const u16* x0, const u16* x1, const float* g, const float* b, float* out) {
    ln_kernel<1, 0><<<MM / 4, 256, 0, stream>>>(x0, x1, g, b, out);
  };
  // gemm modes: 0=plain, 1=relu, 2=res-f32, 3=res-bf16
  auto gemm = [&](const u16* A, int lda, const u16* W, const float* bias,
                  const void* r0, const void* r1, void* out, int ldc,
                  int N2, int K, int mode) {
    int gy = N2 / 128;
    dim3 g((MM / 256) * gy);
    if (mode == 0)
      gemm_bt<false, 0><<<g, 512, 0, stream>>>(A, lda, W, bias, nullptr, nullptr, out, ldc, N2, K, gy);
    else if (mode == 1)
      gemm_bt<true, 0><<<g, 512, 0, stream>>>(A, lda, W, bias, nullptr, nullptr, out, ldc, N2, K, gy);
    else if (mode == 2)
      gemm_bt<false, 1><<<g, 512, 0, stream>>>(A, lda, W, bias, r0, r1, out, ldc, N2, K, gy);
    else
      gemm_bt<false, 2><<<g, 512, 0, stream>>>(A, lda, W, bias, r0, r1, out, ldc, N2, K, gy);
  };
  auto vtrans = [&]() {
    vtrans_kernel<<<dim3(NN / 32, 4, 64), dim3(32, 8), 0, stream>>>(U + 2 * DD, 3 * DD, Vt);
  };
  auto attn = [&]() {
    attn_kernel<<<dim3(512), 512, 0, stream>>>(U, 3 * DD, U + DD, 3 * DD, Vt,
                                               U + 2 * DD, 3 * DD);
  };
  u16* ab = U + 2 * DD;

  // ================= batched pass: rows [0,RR)=model A (enc sT, dec tT), [RR,MM)=model B ======
  // ---- encoder ----
  lnf(sT, tT, enc_ln_g, enc_ln_b, hb);
  gemm(hb, DD, wE, enc_attn_b, nullptr, nullptr, U, 3 * DD, 3 * DD, DD, 0);
  vtrans();
  attn();
  gemm(ab, 3 * DD, wE + 3 * DD * DD, enc_attn_b + 3 * DD, sT, tT, xb, DD, DD, DD, 2);
  lnb(xb, xb1, enc_ln_g + DD, enc_ln_b + DD, hb);
  gemm(hb, DD, wEff1, enc_ff_b1, nullptr, nullptr, U, DFFK, DFFK, DD, 1);
  gemm(U, DFFK, wEff2, enc_ff_b2, xb, xb1, xb, DD, DD, DFFK, 3);
  lnb(xb, xb1, enc_ln_g + 2 * DD, enc_ln_b + 2 * DD, memb);
  // ---- decoder self-attn ----
  lnf(tT, sT, dec_ln_g, dec_ln_b, hb);
  gemm(hb, DD, wS, dec_sa_b, nullptr, nullptr, U, 3 * DD, 3 * DD, DD, 0);
  vtrans();
  attn();
  gemm(ab, 3 * DD, wS + 3 * DD * DD, dec_sa_b + 3 * DD, tT, sT, xb, DD, DD, DD, 2);
  // ---- decoder cross-attn ----
  lnb(xb, xb1, dec_ln_g + DD, dec_ln_b + DD, hb);
  gemm(hb, DD, wC, dec_ca_b, nullptr, nullptr, U, 3 * DD, DD, DD, 0);
  gemm(memb, DD, wC + DD * DD, dec_ca_b + DD, nullptr, nullptr, U + DD, 3 * DD,
       2 * DD, DD, 0);
  vtrans();
  attn();
  gemm(ab, 3 * DD, wC + 3 * DD * DD, dec_ca_b + 3 * DD, xb, xb1, xb, DD, DD, DD, 3);
  // ---- decoder FFN ----
  lnb(xb, xb1, dec_ln_g + 2 * DD, dec_ln_b + 2 * DD, hb);
  gemm(hb, DD, wDff1, dec_ff_b1, nullptr, nullptr, U, DFFK, DFFK, DD, 1);
  gemm(U, DFFK, wDff2, dec_ff_b2, xb, xb1, xb, DD, DD, DFFK, 3);
  lnbf32(xb, xb1, dec_ln_g + 3 * DD, dec_ln_b + 3 * DD, xtmp);
  // ---- output transpose ----
  float* out_f = (float*)d_out;
  out_trans_kernel<<<dim3(DD / 32, NN / 32, 16), dim3(32, 8), 0, stream>>>(
      xtmp, out_f + (size_t)RR * DD, out_f);
}